// Round 4
// baseline (1366.504 us; speedup 1.0000x reference)
//
#include <hip/hip_runtime.h>

// Problem constants (match reference)
#define N_USER  500000
#define N_GROUP 100000
#define N_EDGE  5000000
#define DIM     64

#define SCAN_BLOCK 256
#define SCAN_ELEMS 4096            // elements per scan block (16 per thread)
#define PER_THREAD (SCAN_ELEMS / SCAN_BLOCK)

typedef unsigned int uint32;
typedef unsigned short ushort16;

__device__ inline unsigned short f2bf(float x) {
    uint32 b = __float_as_uint(x);
    uint32 r = (b + 0x7FFFu + ((b >> 16) & 1u)) >> 16;   // round-to-nearest-even
    return (unsigned short)r;
}
__device__ inline float ldt(const float* t, size_t i) { return t[i]; }
__device__ inline float ldt(const unsigned short* t, size_t i) {
    return __uint_as_float((uint32)t[i] << 16);
}

// ---------------------------------------------------------------------------
// Histogram of both endpoints (int atomics, L2-resident counters).
// ---------------------------------------------------------------------------
__global__ void hist_kernel(const int* __restrict__ src,
                            const int* __restrict__ dst,
                            int* __restrict__ cnt_src,
                            int* __restrict__ cnt_dst) {
    int e = blockIdx.x * blockDim.x + threadIdx.x;
    if (e < N_EDGE) {
        atomicAdd(&cnt_src[src[e]], 1);
        atomicAdd(&cnt_dst[dst[e]], 1);
    }
}

// ---------------------------------------------------------------------------
// Exclusive scan (3 stages).
// ---------------------------------------------------------------------------
__global__ void scan1_kernel(const int* __restrict__ cnt,
                             int* __restrict__ off,
                             int* __restrict__ partial,
                             int n) {
    __shared__ int sh[SCAN_BLOCK];
    int tid = threadIdx.x;
    int tbase = blockIdx.x * SCAN_ELEMS + tid * PER_THREAD;
    int local[PER_THREAD];
    int sum = 0;
#pragma unroll
    for (int i = 0; i < PER_THREAD; ++i) {
        int idx = tbase + i;
        int v = (idx < n) ? cnt[idx] : 0;
        local[i] = sum;
        sum += v;
    }
    sh[tid] = sum;
    __syncthreads();
    for (int o = 1; o < SCAN_BLOCK; o <<= 1) {
        int t = (tid >= o) ? sh[tid - o] : 0;
        __syncthreads();
        sh[tid] += t;
        __syncthreads();
    }
    int texc = sh[tid] - sum;
    int blockTotal = sh[SCAN_BLOCK - 1];
#pragma unroll
    for (int i = 0; i < PER_THREAD; ++i) {
        int idx = tbase + i;
        if (idx < n) off[idx] = local[i] + texc;
    }
    if (tid == 0) partial[blockIdx.x] = blockTotal;
}

__global__ void scan2_kernel(int* __restrict__ partial, int nb,
                             int* __restrict__ off_end) {
    __shared__ int sh[SCAN_BLOCK];
    int tid = threadIdx.x;
    int v = (tid < nb) ? partial[tid] : 0;
    sh[tid] = v;
    __syncthreads();
    for (int o = 1; o < SCAN_BLOCK; o <<= 1) {
        int t = (tid >= o) ? sh[tid - o] : 0;
        __syncthreads();
        sh[tid] += t;
        __syncthreads();
    }
    if (tid < nb) partial[tid] = sh[tid] - v;
    if (tid == 0) *off_end = sh[SCAN_BLOCK - 1];
}

__global__ void scan3_kernel(int* __restrict__ off,
                             const int* __restrict__ partial, int n) {
    int base = blockIdx.x * SCAN_ELEMS;
    int add = partial[blockIdx.x];
    for (int i = threadIdx.x; i < SCAN_ELEMS; i += blockDim.x) {
        int idx = base + i;
        if (idx < n) off[idx] += add;
    }
}

// ---------------------------------------------------------------------------
// XCD-sharded bucket fill. Key space split into 8 ranges; block b only
// writes keys in range (b & 7). With round-robin blockIdx->XCD dispatch each
// 2.5MB destination shard is written by ONE XCD's L2 -> lines are fully
// assembled before writeback (kills the 16x partial-line amplification).
// All shards stream the full edge list (NT loads; L3 absorbs re-reads).
// ---------------------------------------------------------------------------
#define DQ ((N_GROUP + 7) / 8)
#define SQ ((N_USER + 7) / 8)
__global__ void fill_sharded(const int* __restrict__ src,
                             const int* __restrict__ dst,
                             const int* __restrict__ off_src,
                             const int* __restrict__ off_dst,
                             int* __restrict__ cur_src,
                             int* __restrict__ cur_dst,
                             int* __restrict__ bucket_src,
                             int* __restrict__ bucket_dst,
                             int nslices) {
    int x = blockIdx.x & 7;
    int slice = blockIdx.x >> 3;
    int dlo = x * DQ, dhi = min(N_GROUP, dlo + DQ);
    int slo = x * SQ, shi = min(N_USER, slo + SQ);
    int stride = nslices * blockDim.x;
    for (int e = slice * blockDim.x + threadIdx.x; e < N_EDGE; e += stride) {
        int g = __builtin_nontemporal_load(&dst[e]);
        int u = __builtin_nontemporal_load(&src[e]);
        if (g >= dlo && g < dhi) {
            int p = atomicAdd(&cur_dst[g], 1);
            bucket_dst[off_dst[g] + p] = u;
        }
        if (u >= slo && u < shi) {
            int p = atomicAdd(&cur_src[u], 1);
            bucket_src[off_src[u] + p] = g;
        }
    }
}

// Single-bucket plain fill (low-ws fallback path).
__global__ void fill_one(const int* __restrict__ key,
                         const int* __restrict__ val,
                         const int* __restrict__ off,
                         int* __restrict__ cur,
                         int* __restrict__ bucket) {
    int e = blockIdx.x * blockDim.x + threadIdx.x;
    if (e < N_EDGE) {
        int k = key[e];
        int p = atomicAdd(&cur[k], 1);
        bucket[off[k] + p] = val[e];
    }
}

// ---------------------------------------------------------------------------
// f32 -> bf16 table conversion (4 floats / thread).
// ---------------------------------------------------------------------------
__global__ void cvt_bf16(const float* __restrict__ in,
                         unsigned short* __restrict__ out, long n4) {
    long i = (long)blockIdx.x * blockDim.x + threadIdx.x;
    if (i >= n4) return;
    const float4 v = ((const float4*)in)[i];
    ushort4 o;
    o.x = f2bf(v.x); o.y = f2bf(v.y); o.z = f2bf(v.z); o.w = f2bf(v.w);
    ((ushort4*)out)[i] = o;
}

// ---------------------------------------------------------------------------
// Gather, 8-deep pipelined; one wave per row, lane = dim. T = float or
// bf16-as-ushort. out16 (optional) emits a bf16 copy of the result row.
// ---------------------------------------------------------------------------
template <int NROW, bool NT, typename T>
__global__ void gather_kernel(const int* __restrict__ off,
                              const int* __restrict__ bucket,
                              const T* __restrict__ table,
                              float* __restrict__ out,
                              unsigned short* __restrict__ out16) {
    int wid = (blockIdx.x * blockDim.x + threadIdx.x) >> 6;
    int lane = threadIdx.x & 63;
    if (wid >= NROW) return;
    int beg = off[wid], end = off[wid + 1];

    float a0 = 0, a1 = 0, a2 = 0, a3 = 0, a4 = 0, a5 = 0, a6 = 0, a7 = 0;
    int e = beg;
    for (; e + 8 <= end; e += 8) {
        int s0 = bucket[e + 0], s1 = bucket[e + 1];
        int s2 = bucket[e + 2], s3 = bucket[e + 3];
        int s4 = bucket[e + 4], s5 = bucket[e + 5];
        int s6 = bucket[e + 6], s7 = bucket[e + 7];
        a0 += ldt(table, (size_t)s0 * DIM + lane);
        a1 += ldt(table, (size_t)s1 * DIM + lane);
        a2 += ldt(table, (size_t)s2 * DIM + lane);
        a3 += ldt(table, (size_t)s3 * DIM + lane);
        a4 += ldt(table, (size_t)s4 * DIM + lane);
        a5 += ldt(table, (size_t)s5 * DIM + lane);
        a6 += ldt(table, (size_t)s6 * DIM + lane);
        a7 += ldt(table, (size_t)s7 * DIM + lane);
    }
    if (e < end) {
        int last = end - 1;
        int i1 = e + 1 < end ? e + 1 : last;
        int i2 = e + 2 < end ? e + 2 : last;
        int i3 = e + 3 < end ? e + 3 : last;
        int i4 = e + 4 < end ? e + 4 : last;
        int i5 = e + 5 < end ? e + 5 : last;
        int i6 = e + 6 < end ? e + 6 : last;
        int i7 = e + 7 < end ? e + 7 : last;
        int s0 = bucket[e], s1 = bucket[i1], s2 = bucket[i2], s3 = bucket[i3];
        int s4 = bucket[i4], s5 = bucket[i5], s6 = bucket[i6], s7 = bucket[i7];
        float w1 = e + 1 < end ? 1.0f : 0.0f;
        float w2 = e + 2 < end ? 1.0f : 0.0f;
        float w3 = e + 3 < end ? 1.0f : 0.0f;
        float w4 = e + 4 < end ? 1.0f : 0.0f;
        float w5 = e + 5 < end ? 1.0f : 0.0f;
        float w6 = e + 6 < end ? 1.0f : 0.0f;
        float w7 = e + 7 < end ? 1.0f : 0.0f;
        a0 +=      ldt(table, (size_t)s0 * DIM + lane);
        a1 += w1 * ldt(table, (size_t)s1 * DIM + lane);
        a2 += w2 * ldt(table, (size_t)s2 * DIM + lane);
        a3 += w3 * ldt(table, (size_t)s3 * DIM + lane);
        a4 += w4 * ldt(table, (size_t)s4 * DIM + lane);
        a5 += w5 * ldt(table, (size_t)s5 * DIM + lane);
        a6 += w6 * ldt(table, (size_t)s6 * DIM + lane);
        a7 += w7 * ldt(table, (size_t)s7 * DIM + lane);
    }
    float acc = ((a0 + a1) + (a2 + a3)) + ((a4 + a5) + (a6 + a7));
    float inv = 1.0f / fmaxf((float)(end - beg), 1.0f);
    float r = acc * inv;
    if (NT) {
        __builtin_nontemporal_store(r, &out[(size_t)wid * DIM + lane]);
    } else {
        out[(size_t)wid * DIM + lane] = r;
    }
    if (out16) out16[(size_t)wid * DIM + lane] = f2bf(r);
}

// ===========================================================================
// Fallback (atomic path) if ws_size is too small for any CSR scratch.
// ===========================================================================
__global__ void deg_kernel(const int* __restrict__ src,
                           const int* __restrict__ dst,
                           float* __restrict__ deg_src,
                           float* __restrict__ deg_dst) {
    int e = blockIdx.x * blockDim.x + threadIdx.x;
    if (e < N_EDGE) {
        unsafeAtomicAdd(&deg_src[src[e]], 1.0f);
        unsafeAtomicAdd(&deg_dst[dst[e]], 1.0f);
    }
}

__global__ void scatter_fwd(const int* __restrict__ src,
                            const int* __restrict__ dst,
                            const float* __restrict__ h_user,
                            float* __restrict__ rst) {
    long idx = (long)blockIdx.x * blockDim.x + threadIdx.x;
    if (idx >= (long)N_EDGE * DIM) return;
    int e = (int)(idx >> 6), d = (int)(idx & 63);
    unsafeAtomicAdd(&rst[(long)dst[e] * DIM + d], h_user[(long)src[e] * DIM + d]);
}

__global__ void norm_kernel(float* __restrict__ x,
                            const float* __restrict__ deg, long total) {
    long idx = (long)blockIdx.x * blockDim.x + threadIdx.x;
    if (idx >= total) return;
    float dg = fmaxf(deg[idx >> 6], 1.0f);
    x[idx] *= (1.0f / dg);
}

__global__ void scatter_bwd(const int* __restrict__ src,
                            const int* __restrict__ dst,
                            const float* __restrict__ rst,
                            float* __restrict__ bsrc) {
    long idx = (long)blockIdx.x * blockDim.x + threadIdx.x;
    if (idx >= (long)N_EDGE * DIM) return;
    int e = (int)(idx >> 6), d = (int)(idx & 63);
    unsafeAtomicAdd(&bsrc[(long)src[e] * DIM + d], rst[(long)dst[e] * DIM + d]);
}

extern "C" void kernel_launch(void* const* d_in, const int* in_sizes, int n_in,
                              void* d_out, int out_size, void* d_ws, size_t ws_size,
                              hipStream_t stream) {
    const float* h_user   = (const float*)d_in[0];
    const int*   edge_src = (const int*)d_in[2];
    const int*   edge_dst = (const int*)d_in[3];

    float* bsrc = (float*)d_out;                   // [N_USER, DIM]
    float* rst  = bsrc + (size_t)N_USER * DIM;     // [N_GROUP, DIM]

    const int BLK = 256;
    const int grid_e = (N_EDGE + BLK - 1) / BLK;

    // ---- scratch layout (ints) ------------------------------------------
    int* ws      = (int*)d_ws;
    int* cnt_dst = ws;                              // N_GROUP
    int* off_dst = cnt_dst + N_GROUP;               // N_GROUP + 1
    int* cnt_src = off_dst + N_GROUP + 1;           // N_USER
    int* off_src = cnt_src + N_USER;                // N_USER + 1
    int* cur_dst = off_src + N_USER + 1;            // N_GROUP
    int* cur_src = cur_dst + N_GROUP;               // N_USER
    int* partial = cur_src + N_USER;                // 256
    int* bucket_dst = partial + 256;                // N_EDGE (by dst -> stores src)
    int* bucket_src = bucket_dst + N_EDGE;          // N_EDGE (by src -> stores dst)
    unsigned short* r16 = (unsigned short*)(bucket_src + N_EDGE);  // N_GROUP*DIM bf16
    unsigned short* h16 = r16 + (size_t)N_GROUP * DIM;             // N_USER*DIM bf16

    size_t need_csr1 = (size_t)((bucket_dst + N_EDGE) - ws) * sizeof(int);
    size_t need_csr2 = (size_t)((bucket_src + N_EDGE) - ws) * sizeof(int);
    size_t need_r16  = need_csr2 + (size_t)N_GROUP * DIM * 2;
    size_t need_full = need_r16 + (size_t)N_USER * DIM * 2;

    int nb_dst = (N_GROUP + SCAN_ELEMS - 1) / SCAN_ELEMS;
    int nb_src = (N_USER + SCAN_ELEMS - 1) / SCAN_ELEMS;

    if (ws_size >= need_csr2) {
        bool use_h16 = (ws_size >= need_full);
        bool use_r16 = (ws_size >= need_r16);

        // Zero cnt/cur region (everything before `partial`).
        hipMemsetAsync(d_ws, 0, (size_t)(partial - ws) * sizeof(int), stream);

        if (use_h16) {
            long n4 = (long)N_USER * DIM / 4;
            cvt_bf16<<<(int)((n4 + BLK - 1) / BLK), BLK, 0, stream>>>(h_user, h16, n4);
        }

        hist_kernel<<<grid_e, BLK, 0, stream>>>(edge_src, edge_dst, cnt_src, cnt_dst);

        scan1_kernel<<<nb_dst, SCAN_BLOCK, 0, stream>>>(cnt_dst, off_dst, partial, N_GROUP);
        scan2_kernel<<<1, SCAN_BLOCK, 0, stream>>>(partial, nb_dst, off_dst + N_GROUP);
        scan3_kernel<<<nb_dst, SCAN_BLOCK, 0, stream>>>(off_dst, partial, N_GROUP);

        scan1_kernel<<<nb_src, SCAN_BLOCK, 0, stream>>>(cnt_src, off_src, partial, N_USER);
        scan2_kernel<<<1, SCAN_BLOCK, 0, stream>>>(partial, nb_src, off_src + N_USER);
        scan3_kernel<<<nb_src, SCAN_BLOCK, 0, stream>>>(off_src, partial, N_USER);

        // XCD-sharded fill: grid = 8 shards x 256 slices.
        const int nslices = 256;
        fill_sharded<<<8 * nslices, BLK, 0, stream>>>(
            edge_src, edge_dst, off_src, off_dst,
            cur_src, cur_dst, bucket_src, bucket_dst, nslices);

        unsigned short* r16p = use_r16 ? r16 : (unsigned short*)nullptr;
        if (use_h16) {
            gather_kernel<N_GROUP, false, unsigned short>
                <<<(N_GROUP * 64 + BLK - 1) / BLK, BLK, 0, stream>>>(
                    off_dst, bucket_dst, h16, rst, r16p);
        } else {
            gather_kernel<N_GROUP, false, float>
                <<<(N_GROUP * 64 + BLK - 1) / BLK, BLK, 0, stream>>>(
                    off_dst, bucket_dst, h_user, rst, r16p);
        }
        if (use_r16) {
            gather_kernel<N_USER, true, unsigned short>
                <<<(int)(((size_t)N_USER * 64 + BLK - 1) / BLK), BLK, 0, stream>>>(
                    off_src, bucket_src, r16, bsrc, nullptr);
        } else {
            gather_kernel<N_USER, true, float>
                <<<(int)(((size_t)N_USER * 64 + BLK - 1) / BLK), BLK, 0, stream>>>(
                    off_src, bucket_src, rst, bsrc, nullptr);
        }
        return;
    }

    if (ws_size >= need_csr1) {
        // Sequential single-bucket path (f32 gathers).
        hipMemsetAsync(d_ws, 0, (size_t)(partial - ws) * sizeof(int), stream);
        hist_kernel<<<grid_e, BLK, 0, stream>>>(edge_src, edge_dst, cnt_src, cnt_dst);

        scan1_kernel<<<nb_dst, SCAN_BLOCK, 0, stream>>>(cnt_dst, off_dst, partial, N_GROUP);
        scan2_kernel<<<1, SCAN_BLOCK, 0, stream>>>(partial, nb_dst, off_dst + N_GROUP);
        scan3_kernel<<<nb_dst, SCAN_BLOCK, 0, stream>>>(off_dst, partial, N_GROUP);

        scan1_kernel<<<nb_src, SCAN_BLOCK, 0, stream>>>(cnt_src, off_src, partial, N_USER);
        scan2_kernel<<<1, SCAN_BLOCK, 0, stream>>>(partial, nb_src, off_src + N_USER);
        scan3_kernel<<<nb_src, SCAN_BLOCK, 0, stream>>>(off_src, partial, N_USER);

        fill_one<<<grid_e, BLK, 0, stream>>>(edge_dst, edge_src, off_dst, cur_dst, bucket_dst);
        gather_kernel<N_GROUP, false, float>
            <<<(N_GROUP * 64 + BLK - 1) / BLK, BLK, 0, stream>>>(
                off_dst, bucket_dst, h_user, rst, nullptr);

        fill_one<<<grid_e, BLK, 0, stream>>>(edge_src, edge_dst, off_src, cur_src, bucket_dst);
        gather_kernel<N_USER, true, float>
            <<<(int)(((size_t)N_USER * 64 + BLK - 1) / BLK), BLK, 0, stream>>>(
                off_src, bucket_dst, rst, bsrc, nullptr);
        return;
    }

    // ---- Fallback: atomic path ------------------------------------------
    float* deg_dst = (float*)d_ws;
    float* deg_src = deg_dst + N_GROUP;
    hipMemsetAsync(d_out, 0, (size_t)(N_USER + N_GROUP) * DIM * sizeof(float), stream);
    hipMemsetAsync(d_ws, 0, (size_t)(N_USER + N_GROUP) * sizeof(float), stream);

    deg_kernel<<<grid_e, BLK, 0, stream>>>(edge_src, edge_dst, deg_src, deg_dst);

    long total_ed = (long)N_EDGE * DIM;
    int grid_ed = (int)((total_ed + BLK - 1) / BLK);
    scatter_fwd<<<grid_ed, BLK, 0, stream>>>(edge_src, edge_dst, h_user, rst);
    long total_g = (long)N_GROUP * DIM;
    norm_kernel<<<(int)((total_g + BLK - 1) / BLK), BLK, 0, stream>>>(rst, deg_dst, total_g);
    scatter_bwd<<<grid_ed, BLK, 0, stream>>>(edge_src, edge_dst, rst, bsrc);
    long total_u = (long)N_USER * DIM;
    norm_kernel<<<(int)((total_u + BLK - 1) / BLK), BLK, 0, stream>>>(bsrc, deg_src, total_u);
}

// Round 5
// 1213.011 us; speedup vs baseline: 1.1265x; 1.1265x over previous
//
#include <hip/hip_runtime.h>

// Problem constants (match reference)
#define N_USER  500000
#define N_GROUP 100000
#define N_EDGE  5000000
#define DIM     64

#define SCAN_BLOCK 256
#define SCAN_ELEMS 4096            // elements per scan block (16 per thread)
#define PER_THREAD (SCAN_ELEMS / SCAN_BLOCK)

// Multisplit coarse-bucket geometry
#define KD_SHIFT 8                                   // 256 group-keys / coarse bucket
#define KS_SHIFT 10                                  // 1024 user-keys / coarse bucket
#define C_DST ((N_GROUP + (1 << KD_SHIFT) - 1) >> KD_SHIFT)   // 391
#define C_SRC ((N_USER  + (1 << KS_SHIFT) - 1) >> KS_SHIFT)   // 489
#define TILE_A 16384                                 // edges per pass-A block

typedef unsigned int uint32;
typedef unsigned long long u64;

__device__ inline unsigned short f2bf(float x) {
    uint32 b = __float_as_uint(x);
    uint32 r = (b + 0x7FFFu + ((b >> 16) & 1u)) >> 16;   // round-to-nearest-even
    return (unsigned short)r;
}
__device__ inline float ldt(const float* t, size_t i) { return t[i]; }
__device__ inline float ldt(const unsigned short* t, size_t i) {
    return __uint_as_float((uint32)t[i] << 16);
}

// ---------------------------------------------------------------------------
// Histogram of both endpoints (int atomics, L2-resident counters).
// ---------------------------------------------------------------------------
__global__ void hist_kernel(const int* __restrict__ src,
                            const int* __restrict__ dst,
                            int* __restrict__ cnt_src,
                            int* __restrict__ cnt_dst) {
    int e = blockIdx.x * blockDim.x + threadIdx.x;
    if (e < N_EDGE) {
        atomicAdd(&cnt_src[src[e]], 1);
        atomicAdd(&cnt_dst[dst[e]], 1);
    }
}

// ---------------------------------------------------------------------------
// Exclusive scan (3 stages).
// ---------------------------------------------------------------------------
__global__ void scan1_kernel(const int* __restrict__ cnt,
                             int* __restrict__ off,
                             int* __restrict__ partial,
                             int n) {
    __shared__ int sh[SCAN_BLOCK];
    int tid = threadIdx.x;
    int tbase = blockIdx.x * SCAN_ELEMS + tid * PER_THREAD;
    int local[PER_THREAD];
    int sum = 0;
#pragma unroll
    for (int i = 0; i < PER_THREAD; ++i) {
        int idx = tbase + i;
        int v = (idx < n) ? cnt[idx] : 0;
        local[i] = sum;
        sum += v;
    }
    sh[tid] = sum;
    __syncthreads();
    for (int o = 1; o < SCAN_BLOCK; o <<= 1) {
        int t = (tid >= o) ? sh[tid - o] : 0;
        __syncthreads();
        sh[tid] += t;
        __syncthreads();
    }
    int texc = sh[tid] - sum;
    int blockTotal = sh[SCAN_BLOCK - 1];
#pragma unroll
    for (int i = 0; i < PER_THREAD; ++i) {
        int idx = tbase + i;
        if (idx < n) off[idx] = local[i] + texc;
    }
    if (tid == 0) partial[blockIdx.x] = blockTotal;
}

__global__ void scan2_kernel(int* __restrict__ partial, int nb,
                             int* __restrict__ off_end) {
    __shared__ int sh[SCAN_BLOCK];
    int tid = threadIdx.x;
    int v = (tid < nb) ? partial[tid] : 0;
    sh[tid] = v;
    __syncthreads();
    for (int o = 1; o < SCAN_BLOCK; o <<= 1) {
        int t = (tid >= o) ? sh[tid - o] : 0;
        __syncthreads();
        sh[tid] += t;
        __syncthreads();
    }
    if (tid < nb) partial[tid] = sh[tid] - v;
    if (tid == 0) *off_end = sh[SCAN_BLOCK - 1];
}

__global__ void scan3_kernel(int* __restrict__ off,
                             const int* __restrict__ partial, int n) {
    int base = blockIdx.x * SCAN_ELEMS;
    int add = partial[blockIdx.x];
    for (int i = threadIdx.x; i < SCAN_ELEMS; i += blockDim.x) {
        int idx = base + i;
        if (idx < n) off[idx] += add;
    }
}

// ---------------------------------------------------------------------------
// Multisplit. Pass A: per-block LDS histogram over coarse buckets, reserve
// contiguous runs via line-padded global cursors, write packed (key,val)
// u64 into private runs -> each 64B line is completed by one block quickly
// (kills partial-line writeback amplification). Coarse regions are the CSR
// off[] subsampled at the bucket stride, so no extra scan is needed.
// ---------------------------------------------------------------------------
__global__ void init_curs(const int* __restrict__ off,
                          int* __restrict__ curs, int C, int shift, int n) {
    int c = blockIdx.x * blockDim.x + threadIdx.x;
    if (c < C) curs[c * 16] = off[min(c << shift, n)];
}

__global__ void passA(const int* __restrict__ src,
                      const int* __restrict__ dst,
                      int* __restrict__ curs_cd,
                      int* __restrict__ curs_cs,
                      u64* __restrict__ coarse_dst,
                      u64* __restrict__ coarse_src) {
    __shared__ int hd[C_DST], bd[C_DST], hs[C_SRC], bs[C_SRC];
    int tid = threadIdx.x;
    long base = (long)blockIdx.x * TILE_A;

    for (int c = tid; c < C_DST; c += blockDim.x) hd[c] = 0;
    for (int c = tid; c < C_SRC; c += blockDim.x) hs[c] = 0;
    __syncthreads();

    // Phase 1: count tile histogram.
    for (int i = tid; i < TILE_A; i += blockDim.x) {
        long e = base + i;
        if (e >= N_EDGE) break;
        int g = dst[e], u = src[e];
        atomicAdd(&hd[g >> KD_SHIFT], 1);
        atomicAdd(&hs[u >> KS_SHIFT], 1);
    }
    __syncthreads();

    // Phase 2: reserve runs (one global atomic per non-empty bucket).
    for (int c = tid; c < C_DST; c += blockDim.x) {
        int n = hd[c];
        bd[c] = n ? atomicAdd(&curs_cd[c * 16], n) : 0;
        hd[c] = 0;
    }
    for (int c = tid; c < C_SRC; c += blockDim.x) {
        int n = hs[c];
        bs[c] = n ? atomicAdd(&curs_cs[c * 16], n) : 0;
        hs[c] = 0;
    }
    __syncthreads();

    // Phase 3: place edges into this block's private runs.
    for (int i = tid; i < TILE_A; i += blockDim.x) {
        long e = base + i;
        if (e >= N_EDGE) break;
        int g = dst[e], u = src[e];
        int cd = g >> KD_SHIFT;
        int pd = atomicAdd(&hd[cd], 1);
        coarse_dst[(size_t)bd[cd] + pd] = ((u64)g << 32) | (uint32)u;
        int cs = u >> KS_SHIFT;
        int ps = atomicAdd(&hs[cs], 1);
        coarse_src[(size_t)bs[cs] + ps] = ((u64)u << 32) | (uint32)g;
    }
}

// Pass B: one workgroup per coarse bucket; scatter to final per-key slots.
// The WG's write target is the bucket's ~25-50KB region -> fully assembled
// lines through a single L2.
__global__ void passB(const u64* __restrict__ coarse,
                      const int* __restrict__ off,
                      int* __restrict__ cur,
                      int* __restrict__ bucket,
                      int shiftK, int n) {
    int c = blockIdx.x;
    int lo = c << shiftK;
    int hi = min(n, (c + 1) << shiftK);
    int beg = off[lo], end = off[hi];
#pragma unroll 4
    for (int i = beg + threadIdx.x; i < end; i += blockDim.x) {
        u64 kv = __builtin_nontemporal_load(&coarse[i]);
        int key = (int)(kv >> 32);
        int val = (int)(kv & 0xffffffffu);
        int p = atomicAdd(&cur[key], 1);
        bucket[off[key] + p] = val;
    }
}

// ---------------------------------------------------------------------------
// Plain fused fill (fallback tier; round-3 behavior).
// ---------------------------------------------------------------------------
__global__ void fill_both(const int* __restrict__ src,
                          const int* __restrict__ dst,
                          const int* __restrict__ off_src,
                          const int* __restrict__ off_dst,
                          int* __restrict__ cur_src,
                          int* __restrict__ cur_dst,
                          int* __restrict__ bucket_src,
                          int* __restrict__ bucket_dst) {
    int e = blockIdx.x * blockDim.x + threadIdx.x;
    if (e < N_EDGE) {
        int u = src[e];
        int g = dst[e];
        int p = atomicAdd(&cur_src[u], 1);
        bucket_src[off_src[u] + p] = g;
        int q = atomicAdd(&cur_dst[g], 1);
        bucket_dst[off_dst[g] + q] = u;
    }
}

__global__ void fill_one(const int* __restrict__ key,
                         const int* __restrict__ val,
                         const int* __restrict__ off,
                         int* __restrict__ cur,
                         int* __restrict__ bucket) {
    int e = blockIdx.x * blockDim.x + threadIdx.x;
    if (e < N_EDGE) {
        int k = key[e];
        int p = atomicAdd(&cur[k], 1);
        bucket[off[k] + p] = val[e];
    }
}

// ---------------------------------------------------------------------------
// f32 -> bf16 table conversion (4 floats / thread).
// ---------------------------------------------------------------------------
__global__ void cvt_bf16(const float* __restrict__ in,
                         unsigned short* __restrict__ out, long n4) {
    long i = (long)blockIdx.x * blockDim.x + threadIdx.x;
    if (i >= n4) return;
    const float4 v = ((const float4*)in)[i];
    ushort4 o;
    o.x = f2bf(v.x); o.y = f2bf(v.y); o.z = f2bf(v.z); o.w = f2bf(v.w);
    ((ushort4*)out)[i] = o;
}

// ---------------------------------------------------------------------------
// Gather, 8-deep pipelined; one wave per row, lane = dim. T = float or
// bf16-as-ushort. out16 (optional) emits a bf16 copy of the result row.
// ---------------------------------------------------------------------------
template <int NROW, bool NT, typename T>
__global__ void gather_kernel(const int* __restrict__ off,
                              const int* __restrict__ bucket,
                              const T* __restrict__ table,
                              float* __restrict__ out,
                              unsigned short* __restrict__ out16) {
    int wid = (blockIdx.x * blockDim.x + threadIdx.x) >> 6;
    int lane = threadIdx.x & 63;
    if (wid >= NROW) return;
    int beg = off[wid], end = off[wid + 1];

    float a0 = 0, a1 = 0, a2 = 0, a3 = 0, a4 = 0, a5 = 0, a6 = 0, a7 = 0;
    int e = beg;
    for (; e + 8 <= end; e += 8) {
        int s0 = bucket[e + 0], s1 = bucket[e + 1];
        int s2 = bucket[e + 2], s3 = bucket[e + 3];
        int s4 = bucket[e + 4], s5 = bucket[e + 5];
        int s6 = bucket[e + 6], s7 = bucket[e + 7];
        a0 += ldt(table, (size_t)s0 * DIM + lane);
        a1 += ldt(table, (size_t)s1 * DIM + lane);
        a2 += ldt(table, (size_t)s2 * DIM + lane);
        a3 += ldt(table, (size_t)s3 * DIM + lane);
        a4 += ldt(table, (size_t)s4 * DIM + lane);
        a5 += ldt(table, (size_t)s5 * DIM + lane);
        a6 += ldt(table, (size_t)s6 * DIM + lane);
        a7 += ldt(table, (size_t)s7 * DIM + lane);
    }
    if (e < end) {
        int last = end - 1;
        int i1 = e + 1 < end ? e + 1 : last;
        int i2 = e + 2 < end ? e + 2 : last;
        int i3 = e + 3 < end ? e + 3 : last;
        int i4 = e + 4 < end ? e + 4 : last;
        int i5 = e + 5 < end ? e + 5 : last;
        int i6 = e + 6 < end ? e + 6 : last;
        int i7 = e + 7 < end ? e + 7 : last;
        int s0 = bucket[e], s1 = bucket[i1], s2 = bucket[i2], s3 = bucket[i3];
        int s4 = bucket[i4], s5 = bucket[i5], s6 = bucket[i6], s7 = bucket[i7];
        float w1 = e + 1 < end ? 1.0f : 0.0f;
        float w2 = e + 2 < end ? 1.0f : 0.0f;
        float w3 = e + 3 < end ? 1.0f : 0.0f;
        float w4 = e + 4 < end ? 1.0f : 0.0f;
        float w5 = e + 5 < end ? 1.0f : 0.0f;
        float w6 = e + 6 < end ? 1.0f : 0.0f;
        float w7 = e + 7 < end ? 1.0f : 0.0f;
        a0 +=      ldt(table, (size_t)s0 * DIM + lane);
        a1 += w1 * ldt(table, (size_t)s1 * DIM + lane);
        a2 += w2 * ldt(table, (size_t)s2 * DIM + lane);
        a3 += w3 * ldt(table, (size_t)s3 * DIM + lane);
        a4 += w4 * ldt(table, (size_t)s4 * DIM + lane);
        a5 += w5 * ldt(table, (size_t)s5 * DIM + lane);
        a6 += w6 * ldt(table, (size_t)s6 * DIM + lane);
        a7 += w7 * ldt(table, (size_t)s7 * DIM + lane);
    }
    float acc = ((a0 + a1) + (a2 + a3)) + ((a4 + a5) + (a6 + a7));
    float inv = 1.0f / fmaxf((float)(end - beg), 1.0f);
    float r = acc * inv;
    if (NT) {
        __builtin_nontemporal_store(r, &out[(size_t)wid * DIM + lane]);
    } else {
        out[(size_t)wid * DIM + lane] = r;
    }
    if (out16) out16[(size_t)wid * DIM + lane] = f2bf(r);
}

// ===========================================================================
// Fallback (atomic path) if ws_size is too small for any CSR scratch.
// ===========================================================================
__global__ void deg_kernel(const int* __restrict__ src,
                           const int* __restrict__ dst,
                           float* __restrict__ deg_src,
                           float* __restrict__ deg_dst) {
    int e = blockIdx.x * blockDim.x + threadIdx.x;
    if (e < N_EDGE) {
        unsafeAtomicAdd(&deg_src[src[e]], 1.0f);
        unsafeAtomicAdd(&deg_dst[dst[e]], 1.0f);
    }
}

__global__ void scatter_fwd(const int* __restrict__ src,
                            const int* __restrict__ dst,
                            const float* __restrict__ h_user,
                            float* __restrict__ rst) {
    long idx = (long)blockIdx.x * blockDim.x + threadIdx.x;
    if (idx >= (long)N_EDGE * DIM) return;
    int e = (int)(idx >> 6), d = (int)(idx & 63);
    unsafeAtomicAdd(&rst[(long)dst[e] * DIM + d], h_user[(long)src[e] * DIM + d]);
}

__global__ void norm_kernel(float* __restrict__ x,
                            const float* __restrict__ deg, long total) {
    long idx = (long)blockIdx.x * blockDim.x + threadIdx.x;
    if (idx >= total) return;
    float dg = fmaxf(deg[idx >> 6], 1.0f);
    x[idx] *= (1.0f / dg);
}

__global__ void scatter_bwd(const int* __restrict__ src,
                            const int* __restrict__ dst,
                            const float* __restrict__ rst,
                            float* __restrict__ bsrc) {
    long idx = (long)blockIdx.x * blockDim.x + threadIdx.x;
    if (idx >= (long)N_EDGE * DIM) return;
    int e = (int)(idx >> 6), d = (int)(idx & 63);
    unsafeAtomicAdd(&bsrc[(long)src[e] * DIM + d], rst[(long)dst[e] * DIM + d]);
}

extern "C" void kernel_launch(void* const* d_in, const int* in_sizes, int n_in,
                              void* d_out, int out_size, void* d_ws, size_t ws_size,
                              hipStream_t stream) {
    const float* h_user   = (const float*)d_in[0];
    const int*   edge_src = (const int*)d_in[2];
    const int*   edge_dst = (const int*)d_in[3];

    float* bsrc = (float*)d_out;                   // [N_USER, DIM]
    float* rst  = bsrc + (size_t)N_USER * DIM;     // [N_GROUP, DIM]

    const int BLK = 256;
    const int grid_e = (N_EDGE + BLK - 1) / BLK;

    // ---- scratch layout -------------------------------------------------
    int* ws      = (int*)d_ws;
    int* cnt_dst = ws;                              // N_GROUP
    int* off_dst = cnt_dst + N_GROUP;               // N_GROUP + 1
    int* cnt_src = off_dst + N_GROUP + 1;           // N_USER
    int* off_src = cnt_src + N_USER;                // N_USER + 1
    int* cur_dst = off_src + N_USER + 1;            // N_GROUP
    int* cur_src = cur_dst + N_GROUP;               // N_USER
    int* partial = cur_src + N_USER;                // 256
    int* bucket_dst = partial + 256;                // N_EDGE (by dst -> stores src)
    int* bucket_src = bucket_dst + N_EDGE;          // N_EDGE (by src -> stores dst)
    unsigned short* r16 = (unsigned short*)(bucket_src + N_EDGE);  // N_GROUP*DIM
    unsigned short* h16 = r16 + (size_t)N_GROUP * DIM;             // N_USER*DIM
    // multisplit extras (8B-aligned tail)
    size_t tail = ((size_t)((char*)(h16 + (size_t)N_USER * DIM) - (char*)d_ws) + 7) & ~(size_t)7;
    int* curs_cd = (int*)((char*)d_ws + tail);      // C_DST * 16 (line-padded)
    int* curs_cs = curs_cd + C_DST * 16;            // C_SRC * 16
    size_t tail2 = ((size_t)((char*)(curs_cs + C_SRC * 16) - (char*)d_ws) + 7) & ~(size_t)7;
    u64* coarse_dst = (u64*)((char*)d_ws + tail2);  // N_EDGE u64
    u64* coarse_src = coarse_dst + N_EDGE;          // N_EDGE u64

    size_t need_csr1 = (size_t)((bucket_dst + N_EDGE) - ws) * sizeof(int);
    size_t need_csr2 = (size_t)((bucket_src + N_EDGE) - ws) * sizeof(int);
    size_t need_r16  = need_csr2 + (size_t)N_GROUP * DIM * 2;
    size_t need_full = need_r16 + (size_t)N_USER * DIM * 2;
    size_t need_ms   = (size_t)((char*)(coarse_src + N_EDGE) - (char*)d_ws);

    int nb_dst = (N_GROUP + SCAN_ELEMS - 1) / SCAN_ELEMS;
    int nb_src = (N_USER + SCAN_ELEMS - 1) / SCAN_ELEMS;

    if (ws_size >= need_csr2) {
        bool use_ms  = (ws_size >= need_ms);
        bool use_h16 = (ws_size >= need_full);
        bool use_r16 = (ws_size >= need_r16);

        // Zero cnt/cur region (everything before `partial`).
        hipMemsetAsync(d_ws, 0, (size_t)(partial - ws) * sizeof(int), stream);

        if (use_h16) {
            long n4 = (long)N_USER * DIM / 4;
            cvt_bf16<<<(int)((n4 + BLK - 1) / BLK), BLK, 0, stream>>>(h_user, h16, n4);
        }

        hist_kernel<<<grid_e, BLK, 0, stream>>>(edge_src, edge_dst, cnt_src, cnt_dst);

        scan1_kernel<<<nb_dst, SCAN_BLOCK, 0, stream>>>(cnt_dst, off_dst, partial, N_GROUP);
        scan2_kernel<<<1, SCAN_BLOCK, 0, stream>>>(partial, nb_dst, off_dst + N_GROUP);
        scan3_kernel<<<nb_dst, SCAN_BLOCK, 0, stream>>>(off_dst, partial, N_GROUP);

        scan1_kernel<<<nb_src, SCAN_BLOCK, 0, stream>>>(cnt_src, off_src, partial, N_USER);
        scan2_kernel<<<1, SCAN_BLOCK, 0, stream>>>(partial, nb_src, off_src + N_USER);
        scan3_kernel<<<nb_src, SCAN_BLOCK, 0, stream>>>(off_src, partial, N_USER);

        if (use_ms) {
            init_curs<<<(C_DST + 255) / 256, 256, 0, stream>>>(off_dst, curs_cd, C_DST, KD_SHIFT, N_GROUP);
            init_curs<<<(C_SRC + 255) / 256, 256, 0, stream>>>(off_src, curs_cs, C_SRC, KS_SHIFT, N_USER);

            int gridA = (N_EDGE + TILE_A - 1) / TILE_A;   // 306
            passA<<<gridA, BLK, 0, stream>>>(edge_src, edge_dst,
                                             curs_cd, curs_cs, coarse_dst, coarse_src);

            passB<<<C_DST, BLK, 0, stream>>>(coarse_dst, off_dst, cur_dst, bucket_dst,
                                             KD_SHIFT, N_GROUP);
            passB<<<C_SRC, BLK, 0, stream>>>(coarse_src, off_src, cur_src, bucket_src,
                                             KS_SHIFT, N_USER);
        } else {
            fill_both<<<grid_e, BLK, 0, stream>>>(
                edge_src, edge_dst, off_src, off_dst,
                cur_src, cur_dst, bucket_src, bucket_dst);
        }

        unsigned short* r16p = use_r16 ? r16 : (unsigned short*)nullptr;
        if (use_h16) {
            gather_kernel<N_GROUP, false, unsigned short>
                <<<(N_GROUP * 64 + BLK - 1) / BLK, BLK, 0, stream>>>(
                    off_dst, bucket_dst, h16, rst, r16p);
        } else {
            gather_kernel<N_GROUP, false, float>
                <<<(N_GROUP * 64 + BLK - 1) / BLK, BLK, 0, stream>>>(
                    off_dst, bucket_dst, h_user, rst, r16p);
        }
        if (use_r16) {
            gather_kernel<N_USER, true, unsigned short>
                <<<(int)(((size_t)N_USER * 64 + BLK - 1) / BLK), BLK, 0, stream>>>(
                    off_src, bucket_src, r16, bsrc, nullptr);
        } else {
            gather_kernel<N_USER, true, float>
                <<<(int)(((size_t)N_USER * 64 + BLK - 1) / BLK), BLK, 0, stream>>>(
                    off_src, bucket_src, rst, bsrc, nullptr);
        }
        return;
    }

    if (ws_size >= need_csr1) {
        // Sequential single-bucket path (f32 gathers).
        hipMemsetAsync(d_ws, 0, (size_t)(partial - ws) * sizeof(int), stream);
        hist_kernel<<<grid_e, BLK, 0, stream>>>(edge_src, edge_dst, cnt_src, cnt_dst);

        scan1_kernel<<<nb_dst, SCAN_BLOCK, 0, stream>>>(cnt_dst, off_dst, partial, N_GROUP);
        scan2_kernel<<<1, SCAN_BLOCK, 0, stream>>>(partial, nb_dst, off_dst + N_GROUP);
        scan3_kernel<<<nb_dst, SCAN_BLOCK, 0, stream>>>(off_dst, partial, N_GROUP);

        scan1_kernel<<<nb_src, SCAN_BLOCK, 0, stream>>>(cnt_src, off_src, partial, N_USER);
        scan2_kernel<<<1, SCAN_BLOCK, 0, stream>>>(partial, nb_src, off_src + N_USER);
        scan3_kernel<<<nb_src, SCAN_BLOCK, 0, stream>>>(off_src, partial, N_USER);

        fill_one<<<grid_e, BLK, 0, stream>>>(edge_dst, edge_src, off_dst, cur_dst, bucket_dst);
        gather_kernel<N_GROUP, false, float>
            <<<(N_GROUP * 64 + BLK - 1) / BLK, BLK, 0, stream>>>(
                off_dst, bucket_dst, h_user, rst, nullptr);

        fill_one<<<grid_e, BLK, 0, stream>>>(edge_src, edge_dst, off_src, cur_src, bucket_dst);
        gather_kernel<N_USER, true, float>
            <<<(int)(((size_t)N_USER * 64 + BLK - 1) / BLK), BLK, 0, stream>>>(
                off_src, bucket_dst, rst, bsrc, nullptr);
        return;
    }

    // ---- Fallback: atomic path ------------------------------------------
    float* deg_dst = (float*)d_ws;
    float* deg_src = deg_dst + N_GROUP;
    hipMemsetAsync(d_out, 0, (size_t)(N_USER + N_GROUP) * DIM * sizeof(float), stream);
    hipMemsetAsync(d_ws, 0, (size_t)(N_USER + N_GROUP) * sizeof(float), stream);

    deg_kernel<<<grid_e, BLK, 0, stream>>>(edge_src, edge_dst, deg_src, deg_dst);

    long total_ed = (long)N_EDGE * DIM;
    int grid_ed = (int)((total_ed + BLK - 1) / BLK);
    scatter_fwd<<<grid_ed, BLK, 0, stream>>>(edge_src, edge_dst, h_user, rst);
    long total_g = (long)N_GROUP * DIM;
    norm_kernel<<<(int)((total_g + BLK - 1) / BLK), BLK, 0, stream>>>(rst, deg_dst, total_g);
    scatter_bwd<<<grid_ed, BLK, 0, stream>>>(edge_src, edge_dst, rst, bsrc);
    long total_u = (long)N_USER * DIM;
    norm_kernel<<<(int)((total_u + BLK - 1) / BLK), BLK, 0, stream>>>(bsrc, deg_src, total_u);
}

// Round 6
// 740.512 us; speedup vs baseline: 1.8454x; 1.6381x over previous
//
#include <hip/hip_runtime.h>

// Problem constants (match reference)
#define N_USER  500000
#define N_GROUP 100000
#define N_EDGE  5000000
#define DIM     64

#define SCAN_BLOCK 256
#define SCAN_ELEMS 4096            // elements per scan block (16 per thread)
#define PER_THREAD (SCAN_ELEMS / SCAN_BLOCK)

// Multisplit coarse-bucket geometry
#define KD_SHIFT 8                                   // 256 group-keys / coarse bucket
#define KS_SHIFT 10                                  // 1024 user-keys / coarse bucket
#define C_DST ((N_GROUP + (1 << KD_SHIFT) - 1) >> KD_SHIFT)   // 391
#define C_SRC ((N_USER  + (1 << KS_SHIFT) - 1) >> KS_SHIFT)   // 489
#define TILE_A 16384                                 // edges per pass-A block

typedef unsigned int uint32;
typedef unsigned long long u64;

__device__ inline unsigned short f2bf(float x) {
    uint32 b = __float_as_uint(x);
    uint32 r = (b + 0x7FFFu + ((b >> 16) & 1u)) >> 16;   // round-to-nearest-even
    return (unsigned short)r;
}
__device__ inline float ldt(const float* t, size_t i) { return t[i]; }
__device__ inline float ldt(const unsigned short* t, size_t i) {
    return __uint_as_float((uint32)t[i] << 16);
}

// ---------------------------------------------------------------------------
// Coarse histogram: per-block LDS hist over 391+489 coarse buckets, merged
// with one global atomic per (block, nonempty bucket) -> ~270K atomics total
// (vs 10M fine-grained write-through atomics of the old hist_kernel).
// ---------------------------------------------------------------------------
__global__ void coarse_count(const int* __restrict__ src,
                             const int* __restrict__ dst,
                             int* __restrict__ ccd,
                             int* __restrict__ ccs) {
    __shared__ int hd[C_DST], hs[C_SRC];
    int tid = threadIdx.x;
    long base = (long)blockIdx.x * TILE_A;
    for (int k = tid; k < C_DST; k += blockDim.x) hd[k] = 0;
    for (int k = tid; k < C_SRC; k += blockDim.x) hs[k] = 0;
    __syncthreads();
    for (int i = tid; i < TILE_A; i += blockDim.x) {
        long e = base + i;
        if (e >= N_EDGE) break;
        atomicAdd(&hd[dst[e] >> KD_SHIFT], 1);
        atomicAdd(&hs[src[e] >> KS_SHIFT], 1);
    }
    __syncthreads();
    for (int k = tid; k < C_DST; k += blockDim.x) if (hd[k]) atomicAdd(&ccd[k], hd[k]);
    for (int k = tid; k < C_SRC; k += blockDim.x) if (hs[k]) atomicAdd(&ccs[k], hs[k]);
}

// ---------------------------------------------------------------------------
// Exclusive scan (3 stages) — used single-block for coarse offsets, and
// multi-block only on the fallback tiers.
// ---------------------------------------------------------------------------
__global__ void scan1_kernel(const int* __restrict__ cnt,
                             int* __restrict__ off,
                             int* __restrict__ partial,
                             int n) {
    __shared__ int sh[SCAN_BLOCK];
    int tid = threadIdx.x;
    int tbase = blockIdx.x * SCAN_ELEMS + tid * PER_THREAD;
    int local[PER_THREAD];
    int sum = 0;
#pragma unroll
    for (int i = 0; i < PER_THREAD; ++i) {
        int idx = tbase + i;
        int v = (idx < n) ? cnt[idx] : 0;
        local[i] = sum;
        sum += v;
    }
    sh[tid] = sum;
    __syncthreads();
    for (int o = 1; o < SCAN_BLOCK; o <<= 1) {
        int t = (tid >= o) ? sh[tid - o] : 0;
        __syncthreads();
        sh[tid] += t;
        __syncthreads();
    }
    int texc = sh[tid] - sum;
    int blockTotal = sh[SCAN_BLOCK - 1];
#pragma unroll
    for (int i = 0; i < PER_THREAD; ++i) {
        int idx = tbase + i;
        if (idx < n) off[idx] = local[i] + texc;
    }
    if (tid == 0) partial[blockIdx.x] = blockTotal;
}

__global__ void scan2_kernel(int* __restrict__ partial, int nb,
                             int* __restrict__ off_end) {
    __shared__ int sh[SCAN_BLOCK];
    int tid = threadIdx.x;
    int v = (tid < nb) ? partial[tid] : 0;
    sh[tid] = v;
    __syncthreads();
    for (int o = 1; o < SCAN_BLOCK; o <<= 1) {
        int t = (tid >= o) ? sh[tid - o] : 0;
        __syncthreads();
        sh[tid] += t;
        __syncthreads();
    }
    if (tid < nb) partial[tid] = sh[tid] - v;
    if (tid == 0) *off_end = sh[SCAN_BLOCK - 1];
}

__global__ void scan3_kernel(int* __restrict__ off,
                             const int* __restrict__ partial, int n) {
    int base = blockIdx.x * SCAN_ELEMS;
    int add = partial[blockIdx.x];
    for (int i = threadIdx.x; i < SCAN_ELEMS; i += blockDim.x) {
        int idx = base + i;
        if (idx < n) off[idx] += add;
    }
}

// ---------------------------------------------------------------------------
// init cursors from coarse offsets (line-padded).
// ---------------------------------------------------------------------------
__global__ void init_curs(const int* __restrict__ off,
                          int* __restrict__ curs, int C, int shift, int n) {
    int c = blockIdx.x * blockDim.x + threadIdx.x;
    if (c < C) curs[c * 16] = off[min(c << shift, n)];
}

__global__ void set_tail(int* __restrict__ off_d, int* __restrict__ off_s) {
    if (threadIdx.x == 0 && blockIdx.x == 0) {
        off_d[N_GROUP] = N_EDGE;
        off_s[N_USER]  = N_EDGE;
    }
}

// ---------------------------------------------------------------------------
// Pass A: per-block LDS histogram over coarse buckets, reserve contiguous
// runs via line-padded global cursors, write packed (key,val) u64 into
// private runs -> each 64B line is completed by one block quickly.
// ---------------------------------------------------------------------------
__global__ void passA(const int* __restrict__ src,
                      const int* __restrict__ dst,
                      int* __restrict__ curs_cd,
                      int* __restrict__ curs_cs,
                      u64* __restrict__ coarse_dst,
                      u64* __restrict__ coarse_src) {
    __shared__ int hd[C_DST], bd[C_DST], hs[C_SRC], bs[C_SRC];
    int tid = threadIdx.x;
    long base = (long)blockIdx.x * TILE_A;

    for (int c = tid; c < C_DST; c += blockDim.x) hd[c] = 0;
    for (int c = tid; c < C_SRC; c += blockDim.x) hs[c] = 0;
    __syncthreads();

    for (int i = tid; i < TILE_A; i += blockDim.x) {
        long e = base + i;
        if (e >= N_EDGE) break;
        int g = dst[e], u = src[e];
        atomicAdd(&hd[g >> KD_SHIFT], 1);
        atomicAdd(&hs[u >> KS_SHIFT], 1);
    }
    __syncthreads();

    for (int c = tid; c < C_DST; c += blockDim.x) {
        int n = hd[c];
        bd[c] = n ? atomicAdd(&curs_cd[c * 16], n) : 0;
        hd[c] = 0;
    }
    for (int c = tid; c < C_SRC; c += blockDim.x) {
        int n = hs[c];
        bs[c] = n ? atomicAdd(&curs_cs[c * 16], n) : 0;
        hs[c] = 0;
    }
    __syncthreads();

    for (int i = tid; i < TILE_A; i += blockDim.x) {
        long e = base + i;
        if (e >= N_EDGE) break;
        int g = dst[e], u = src[e];
        int cd = g >> KD_SHIFT;
        int pd = atomicAdd(&hd[cd], 1);
        coarse_dst[(size_t)bd[cd] + pd] = ((u64)g << 32) | (uint32)u;
        int cs = u >> KS_SHIFT;
        int ps = atomicAdd(&hs[cs], 1);
        coarse_src[(size_t)bs[cs] + ps] = ((u64)u << 32) | (uint32)g;
    }
}

// ---------------------------------------------------------------------------
// Pass B: one workgroup per coarse bucket. LDS fine-histogram of the <=2^SHIFT
// key range, LDS exclusive scan -> writes the global off[] slice, then
// scatters values to final slots with LDS cursors (no global cur[] atomics).
// ---------------------------------------------------------------------------
template <int SHIFT>
__global__ void passB_t(const u64* __restrict__ coarse,
                        const int* __restrict__ coarse_off,
                        int* __restrict__ off,
                        int* __restrict__ bucket,
                        int n) {
    const int NK = 1 << SHIFT;
    const int PT = NK / 256;
    __shared__ int hist[NK];
    __shared__ int tsum[256];
    int tid = threadIdx.x;
    int c = blockIdx.x;
    int lo = c << SHIFT;
    int beg = coarse_off[c], end = coarse_off[c + 1];

    for (int k = tid; k < NK; k += 256) hist[k] = 0;
    __syncthreads();

    for (int i = beg + tid; i < end; i += 256) {
        int key = (int)(__builtin_nontemporal_load(&coarse[i]) >> 32);
        atomicAdd(&hist[key - lo], 1);
    }
    __syncthreads();

    // exclusive scan of hist[0..NK)
    int local[PT];
    int sum = 0;
#pragma unroll
    for (int i = 0; i < PT; ++i) {
        int v = hist[tid * PT + i];
        local[i] = sum;
        sum += v;
    }
    tsum[tid] = sum;
    __syncthreads();
    for (int o = 1; o < 256; o <<= 1) {
        int t = (tid >= o) ? tsum[tid - o] : 0;
        __syncthreads();
        tsum[tid] += t;
        __syncthreads();
    }
    int texc = tsum[tid] - sum;
    __syncthreads();
#pragma unroll
    for (int i = 0; i < PT; ++i) {
        int k = tid * PT + i;
        int excl = texc + local[i];
        hist[k] = excl;                            // cursor seed
        if (lo + k < n) off[lo + k] = beg + excl;  // global CSR offsets
    }
    __syncthreads();

    for (int i = beg + tid; i < end; i += 256) {
        u64 kv = __builtin_nontemporal_load(&coarse[i]);
        int key = (int)(kv >> 32);
        int p = atomicAdd(&hist[key - lo], 1);
        bucket[beg + p] = (int)(kv & 0xffffffffu);
    }
}

// ---------------------------------------------------------------------------
// Fallback-tier kernels (unchanged behavior).
// ---------------------------------------------------------------------------
__global__ void hist_kernel(const int* __restrict__ src,
                            const int* __restrict__ dst,
                            int* __restrict__ cnt_src,
                            int* __restrict__ cnt_dst) {
    int e = blockIdx.x * blockDim.x + threadIdx.x;
    if (e < N_EDGE) {
        atomicAdd(&cnt_src[src[e]], 1);
        atomicAdd(&cnt_dst[dst[e]], 1);
    }
}

__global__ void fill_both(const int* __restrict__ src,
                          const int* __restrict__ dst,
                          const int* __restrict__ off_src,
                          const int* __restrict__ off_dst,
                          int* __restrict__ cur_src,
                          int* __restrict__ cur_dst,
                          int* __restrict__ bucket_src,
                          int* __restrict__ bucket_dst) {
    int e = blockIdx.x * blockDim.x + threadIdx.x;
    if (e < N_EDGE) {
        int u = src[e];
        int g = dst[e];
        int p = atomicAdd(&cur_src[u], 1);
        bucket_src[off_src[u] + p] = g;
        int q = atomicAdd(&cur_dst[g], 1);
        bucket_dst[off_dst[g] + q] = u;
    }
}

__global__ void fill_one(const int* __restrict__ key,
                         const int* __restrict__ val,
                         const int* __restrict__ off,
                         int* __restrict__ cur,
                         int* __restrict__ bucket) {
    int e = blockIdx.x * blockDim.x + threadIdx.x;
    if (e < N_EDGE) {
        int k = key[e];
        int p = atomicAdd(&cur[k], 1);
        bucket[off[k] + p] = val[e];
    }
}

// ---------------------------------------------------------------------------
// f32 -> bf16 table conversion (4 floats / thread).
// ---------------------------------------------------------------------------
__global__ void cvt_bf16(const float* __restrict__ in,
                         unsigned short* __restrict__ out, long n4) {
    long i = (long)blockIdx.x * blockDim.x + threadIdx.x;
    if (i >= n4) return;
    const float4 v = ((const float4*)in)[i];
    ushort4 o;
    o.x = f2bf(v.x); o.y = f2bf(v.y); o.z = f2bf(v.z); o.w = f2bf(v.w);
    ((ushort4*)out)[i] = o;
}

// ---------------------------------------------------------------------------
// Gather, 8-deep pipelined; one wave per row, lane = dim. T = float or
// bf16-as-ushort. out16 (optional) emits a bf16 copy of the result row.
// ---------------------------------------------------------------------------
template <int NROW, bool NT, typename T>
__global__ void gather_kernel(const int* __restrict__ off,
                              const int* __restrict__ bucket,
                              const T* __restrict__ table,
                              float* __restrict__ out,
                              unsigned short* __restrict__ out16) {
    int wid = (blockIdx.x * blockDim.x + threadIdx.x) >> 6;
    int lane = threadIdx.x & 63;
    if (wid >= NROW) return;
    int beg = off[wid], end = off[wid + 1];

    float a0 = 0, a1 = 0, a2 = 0, a3 = 0, a4 = 0, a5 = 0, a6 = 0, a7 = 0;
    int e = beg;
    for (; e + 8 <= end; e += 8) {
        int s0 = bucket[e + 0], s1 = bucket[e + 1];
        int s2 = bucket[e + 2], s3 = bucket[e + 3];
        int s4 = bucket[e + 4], s5 = bucket[e + 5];
        int s6 = bucket[e + 6], s7 = bucket[e + 7];
        a0 += ldt(table, (size_t)s0 * DIM + lane);
        a1 += ldt(table, (size_t)s1 * DIM + lane);
        a2 += ldt(table, (size_t)s2 * DIM + lane);
        a3 += ldt(table, (size_t)s3 * DIM + lane);
        a4 += ldt(table, (size_t)s4 * DIM + lane);
        a5 += ldt(table, (size_t)s5 * DIM + lane);
        a6 += ldt(table, (size_t)s6 * DIM + lane);
        a7 += ldt(table, (size_t)s7 * DIM + lane);
    }
    if (e < end) {
        int last = end - 1;
        int i1 = e + 1 < end ? e + 1 : last;
        int i2 = e + 2 < end ? e + 2 : last;
        int i3 = e + 3 < end ? e + 3 : last;
        int i4 = e + 4 < end ? e + 4 : last;
        int i5 = e + 5 < end ? e + 5 : last;
        int i6 = e + 6 < end ? e + 6 : last;
        int i7 = e + 7 < end ? e + 7 : last;
        int s0 = bucket[e], s1 = bucket[i1], s2 = bucket[i2], s3 = bucket[i3];
        int s4 = bucket[i4], s5 = bucket[i5], s6 = bucket[i6], s7 = bucket[i7];
        float w1 = e + 1 < end ? 1.0f : 0.0f;
        float w2 = e + 2 < end ? 1.0f : 0.0f;
        float w3 = e + 3 < end ? 1.0f : 0.0f;
        float w4 = e + 4 < end ? 1.0f : 0.0f;
        float w5 = e + 5 < end ? 1.0f : 0.0f;
        float w6 = e + 6 < end ? 1.0f : 0.0f;
        float w7 = e + 7 < end ? 1.0f : 0.0f;
        a0 +=      ldt(table, (size_t)s0 * DIM + lane);
        a1 += w1 * ldt(table, (size_t)s1 * DIM + lane);
        a2 += w2 * ldt(table, (size_t)s2 * DIM + lane);
        a3 += w3 * ldt(table, (size_t)s3 * DIM + lane);
        a4 += w4 * ldt(table, (size_t)s4 * DIM + lane);
        a5 += w5 * ldt(table, (size_t)s5 * DIM + lane);
        a6 += w6 * ldt(table, (size_t)s6 * DIM + lane);
        a7 += w7 * ldt(table, (size_t)s7 * DIM + lane);
    }
    float acc = ((a0 + a1) + (a2 + a3)) + ((a4 + a5) + (a6 + a7));
    float inv = 1.0f / fmaxf((float)(end - beg), 1.0f);
    float r = acc * inv;
    if (NT) {
        __builtin_nontemporal_store(r, &out[(size_t)wid * DIM + lane]);
    } else {
        out[(size_t)wid * DIM + lane] = r;
    }
    if (out16) out16[(size_t)wid * DIM + lane] = f2bf(r);
}

// ===========================================================================
// Last-resort fallback (atomic path).
// ===========================================================================
__global__ void deg_kernel(const int* __restrict__ src,
                           const int* __restrict__ dst,
                           float* __restrict__ deg_src,
                           float* __restrict__ deg_dst) {
    int e = blockIdx.x * blockDim.x + threadIdx.x;
    if (e < N_EDGE) {
        unsafeAtomicAdd(&deg_src[src[e]], 1.0f);
        unsafeAtomicAdd(&deg_dst[dst[e]], 1.0f);
    }
}

__global__ void scatter_fwd(const int* __restrict__ src,
                            const int* __restrict__ dst,
                            const float* __restrict__ h_user,
                            float* __restrict__ rst) {
    long idx = (long)blockIdx.x * blockDim.x + threadIdx.x;
    if (idx >= (long)N_EDGE * DIM) return;
    int e = (int)(idx >> 6), d = (int)(idx & 63);
    unsafeAtomicAdd(&rst[(long)dst[e] * DIM + d], h_user[(long)src[e] * DIM + d]);
}

__global__ void norm_kernel(float* __restrict__ x,
                            const float* __restrict__ deg, long total) {
    long idx = (long)blockIdx.x * blockDim.x + threadIdx.x;
    if (idx >= total) return;
    float dg = fmaxf(deg[idx >> 6], 1.0f);
    x[idx] *= (1.0f / dg);
}

__global__ void scatter_bwd(const int* __restrict__ src,
                            const int* __restrict__ dst,
                            const float* __restrict__ rst,
                            float* __restrict__ bsrc) {
    long idx = (long)blockIdx.x * blockDim.x + threadIdx.x;
    if (idx >= (long)N_EDGE * DIM) return;
    int e = (int)(idx >> 6), d = (int)(idx & 63);
    unsafeAtomicAdd(&bsrc[(long)src[e] * DIM + d], rst[(long)dst[e] * DIM + d]);
}

extern "C" void kernel_launch(void* const* d_in, const int* in_sizes, int n_in,
                              void* d_out, int out_size, void* d_ws, size_t ws_size,
                              hipStream_t stream) {
    const float* h_user   = (const float*)d_in[0];
    const int*   edge_src = (const int*)d_in[2];
    const int*   edge_dst = (const int*)d_in[3];

    float* bsrc = (float*)d_out;                   // [N_USER, DIM]
    float* rst  = bsrc + (size_t)N_USER * DIM;     // [N_GROUP, DIM]

    const int BLK = 256;
    const int grid_e = (N_EDGE + BLK - 1) / BLK;

    // ---- scratch layout (header kept fallback-compatible) ---------------
    int* ws      = (int*)d_ws;
    int* cnt_dst = ws;                              // N_GROUP        (fallback only)
    int* off_dst = cnt_dst + N_GROUP;               // N_GROUP + 1
    int* cnt_src = off_dst + N_GROUP + 1;           // N_USER         (fallback only)
    int* off_src = cnt_src + N_USER;                // N_USER + 1
    int* cur_dst = off_src + N_USER + 1;            // N_GROUP        (fallback only)
    int* cur_src = cur_dst + N_GROUP;               // N_USER         (fallback only)
    int* partial = cur_src + N_USER;                // 256
    int* bucket_dst = partial + 256;                // N_EDGE (by dst -> stores src)
    int* bucket_src = bucket_dst + N_EDGE;          // N_EDGE (by src -> stores dst)
    unsigned short* r16 = (unsigned short*)(bucket_src + N_EDGE);  // N_GROUP*DIM
    unsigned short* h16 = r16 + (size_t)N_GROUP * DIM;             // N_USER*DIM
    // multisplit extras (8B-aligned tail)
    size_t tail = ((size_t)((char*)(h16 + (size_t)N_USER * DIM) - (char*)d_ws) + 7) & ~(size_t)7;
    int* curs_cd = (int*)((char*)d_ws + tail);      // C_DST * 16 (line-padded)
    int* curs_cs = curs_cd + C_DST * 16;            // C_SRC * 16
    int* ccnt_d  = curs_cs + C_SRC * 16;            // C_DST  coarse counts
    int* ccnt_s  = ccnt_d + C_DST;                  // C_SRC  coarse counts
    int* coff_d  = ccnt_s + C_SRC;                  // C_DST + 1
    int* coff_s  = coff_d + C_DST + 1;              // C_SRC + 1
    size_t tail2 = ((size_t)((char*)(coff_s + C_SRC + 1) - (char*)d_ws) + 7) & ~(size_t)7;
    u64* coarse_dst = (u64*)((char*)d_ws + tail2);  // N_EDGE u64
    u64* coarse_src = coarse_dst + N_EDGE;          // N_EDGE u64

    size_t need_csr1 = (size_t)((bucket_dst + N_EDGE) - ws) * sizeof(int);
    size_t need_csr2 = (size_t)((bucket_src + N_EDGE) - ws) * sizeof(int);
    size_t need_r16  = need_csr2 + (size_t)N_GROUP * DIM * 2;
    size_t need_full = need_r16 + (size_t)N_USER * DIM * 2;
    size_t need_ms   = (size_t)((char*)(coarse_src + N_EDGE) - (char*)d_ws);

    int nb_dst = (N_GROUP + SCAN_ELEMS - 1) / SCAN_ELEMS;
    int nb_src = (N_USER + SCAN_ELEMS - 1) / SCAN_ELEMS;

    if (ws_size >= need_ms) {
        // ---- multisplit path, no fine-grained global histogram ----------
        bool use_h16 = (ws_size >= need_full);
        bool use_r16 = (ws_size >= need_r16);

        // Zero only the coarse counters (tiny).
        hipMemsetAsync(ccnt_d, 0, (size_t)(C_DST + C_SRC) * sizeof(int), stream);

        if (use_h16) {
            long n4 = (long)N_USER * DIM / 4;
            cvt_bf16<<<(int)((n4 + BLK - 1) / BLK), BLK, 0, stream>>>(h_user, h16, n4);
        }

        int gridA = (N_EDGE + TILE_A - 1) / TILE_A;   // 306
        coarse_count<<<gridA, BLK, 0, stream>>>(edge_src, edge_dst, ccnt_d, ccnt_s);

        // Single-block scans of the coarse counts (C <= 4096).
        scan1_kernel<<<1, SCAN_BLOCK, 0, stream>>>(ccnt_d, coff_d, partial, C_DST);
        scan2_kernel<<<1, SCAN_BLOCK, 0, stream>>>(partial, 1, coff_d + C_DST);
        scan1_kernel<<<1, SCAN_BLOCK, 0, stream>>>(ccnt_s, coff_s, partial, C_SRC);
        scan2_kernel<<<1, SCAN_BLOCK, 0, stream>>>(partial, 1, coff_s + C_SRC);

        init_curs<<<(C_DST + 255) / 256, 256, 0, stream>>>(coff_d, curs_cd, C_DST, 0, C_DST);
        init_curs<<<(C_SRC + 255) / 256, 256, 0, stream>>>(coff_s, curs_cs, C_SRC, 0, C_SRC);

        passA<<<gridA, BLK, 0, stream>>>(edge_src, edge_dst,
                                         curs_cd, curs_cs, coarse_dst, coarse_src);

        passB_t<KD_SHIFT><<<C_DST, 256, 0, stream>>>(coarse_dst, coff_d,
                                                     off_dst, bucket_dst, N_GROUP);
        passB_t<KS_SHIFT><<<C_SRC, 256, 0, stream>>>(coarse_src, coff_s,
                                                     off_src, bucket_src, N_USER);
        set_tail<<<1, 64, 0, stream>>>(off_dst, off_src);

        unsigned short* r16p = use_r16 ? r16 : (unsigned short*)nullptr;
        if (use_h16) {
            gather_kernel<N_GROUP, false, unsigned short>
                <<<(N_GROUP * 64 + BLK - 1) / BLK, BLK, 0, stream>>>(
                    off_dst, bucket_dst, h16, rst, r16p);
        } else {
            gather_kernel<N_GROUP, false, float>
                <<<(N_GROUP * 64 + BLK - 1) / BLK, BLK, 0, stream>>>(
                    off_dst, bucket_dst, h_user, rst, r16p);
        }
        if (use_r16) {
            gather_kernel<N_USER, true, unsigned short>
                <<<(int)(((size_t)N_USER * 64 + BLK - 1) / BLK), BLK, 0, stream>>>(
                    off_src, bucket_src, r16, bsrc, nullptr);
        } else {
            gather_kernel<N_USER, true, float>
                <<<(int)(((size_t)N_USER * 64 + BLK - 1) / BLK), BLK, 0, stream>>>(
                    off_src, bucket_src, rst, bsrc, nullptr);
        }
        return;
    }

    if (ws_size >= need_csr2) {
        // ---- fallback: hist+scan+fused fill (round-3 structure) ---------
        bool use_h16 = (ws_size >= need_full);
        bool use_r16 = (ws_size >= need_r16);

        hipMemsetAsync(d_ws, 0, (size_t)(partial - ws) * sizeof(int), stream);

        if (use_h16) {
            long n4 = (long)N_USER * DIM / 4;
            cvt_bf16<<<(int)((n4 + BLK - 1) / BLK), BLK, 0, stream>>>(h_user, h16, n4);
        }

        hist_kernel<<<grid_e, BLK, 0, stream>>>(edge_src, edge_dst, cnt_src, cnt_dst);

        scan1_kernel<<<nb_dst, SCAN_BLOCK, 0, stream>>>(cnt_dst, off_dst, partial, N_GROUP);
        scan2_kernel<<<1, SCAN_BLOCK, 0, stream>>>(partial, nb_dst, off_dst + N_GROUP);
        scan3_kernel<<<nb_dst, SCAN_BLOCK, 0, stream>>>(off_dst, partial, N_GROUP);

        scan1_kernel<<<nb_src, SCAN_BLOCK, 0, stream>>>(cnt_src, off_src, partial, N_USER);
        scan2_kernel<<<1, SCAN_BLOCK, 0, stream>>>(partial, nb_src, off_src + N_USER);
        scan3_kernel<<<nb_src, SCAN_BLOCK, 0, stream>>>(off_src, partial, N_USER);

        fill_both<<<grid_e, BLK, 0, stream>>>(
            edge_src, edge_dst, off_src, off_dst,
            cur_src, cur_dst, bucket_src, bucket_dst);

        unsigned short* r16p = use_r16 ? r16 : (unsigned short*)nullptr;
        if (use_h16) {
            gather_kernel<N_GROUP, false, unsigned short>
                <<<(N_GROUP * 64 + BLK - 1) / BLK, BLK, 0, stream>>>(
                    off_dst, bucket_dst, h16, rst, r16p);
        } else {
            gather_kernel<N_GROUP, false, float>
                <<<(N_GROUP * 64 + BLK - 1) / BLK, BLK, 0, stream>>>(
                    off_dst, bucket_dst, h_user, rst, r16p);
        }
        if (use_r16) {
            gather_kernel<N_USER, true, unsigned short>
                <<<(int)(((size_t)N_USER * 64 + BLK - 1) / BLK), BLK, 0, stream>>>(
                    off_src, bucket_src, r16, bsrc, nullptr);
        } else {
            gather_kernel<N_USER, true, float>
                <<<(int)(((size_t)N_USER * 64 + BLK - 1) / BLK), BLK, 0, stream>>>(
                    off_src, bucket_src, rst, bsrc, nullptr);
        }
        return;
    }

    if (ws_size >= need_csr1) {
        // Sequential single-bucket path (f32 gathers).
        hipMemsetAsync(d_ws, 0, (size_t)(partial - ws) * sizeof(int), stream);
        hist_kernel<<<grid_e, BLK, 0, stream>>>(edge_src, edge_dst, cnt_src, cnt_dst);

        scan1_kernel<<<nb_dst, SCAN_BLOCK, 0, stream>>>(cnt_dst, off_dst, partial, N_GROUP);
        scan2_kernel<<<1, SCAN_BLOCK, 0, stream>>>(partial, nb_dst, off_dst + N_GROUP);
        scan3_kernel<<<nb_dst, SCAN_BLOCK, 0, stream>>>(off_dst, partial, N_GROUP);

        scan1_kernel<<<nb_src, SCAN_BLOCK, 0, stream>>>(cnt_src, off_src, partial, N_USER);
        scan2_kernel<<<1, SCAN_BLOCK, 0, stream>>>(partial, nb_src, off_src + N_USER);
        scan3_kernel<<<nb_src, SCAN_BLOCK, 0, stream>>>(off_src, partial, N_USER);

        fill_one<<<grid_e, BLK, 0, stream>>>(edge_dst, edge_src, off_dst, cur_dst, bucket_dst);
        gather_kernel<N_GROUP, false, float>
            <<<(N_GROUP * 64 + BLK - 1) / BLK, BLK, 0, stream>>>(
                off_dst, bucket_dst, h_user, rst, nullptr);

        fill_one<<<grid_e, BLK, 0, stream>>>(edge_src, edge_dst, off_src, cur_src, bucket_dst);
        gather_kernel<N_USER, true, float>
            <<<(int)(((size_t)N_USER * 64 + BLK - 1) / BLK), BLK, 0, stream>>>(
                off_src, bucket_dst, rst, bsrc, nullptr);
        return;
    }

    // ---- Fallback: atomic path ------------------------------------------
    float* deg_dst = (float*)d_ws;
    float* deg_src = deg_dst + N_GROUP;
    hipMemsetAsync(d_out, 0, (size_t)(N_USER + N_GROUP) * DIM * sizeof(float), stream);
    hipMemsetAsync(d_ws, 0, (size_t)(N_USER + N_GROUP) * sizeof(float), stream);

    deg_kernel<<<grid_e, BLK, 0, stream>>>(edge_src, edge_dst, deg_src, deg_dst);

    long total_ed = (long)N_EDGE * DIM;
    int grid_ed = (int)((total_ed + BLK - 1) / BLK);
    scatter_fwd<<<grid_ed, BLK, 0, stream>>>(edge_src, edge_dst, h_user, rst);
    long total_g = (long)N_GROUP * DIM;
    norm_kernel<<<(int)((total_g + BLK - 1) / BLK), BLK, 0, stream>>>(rst, deg_dst, total_g);
    scatter_bwd<<<grid_ed, BLK, 0, stream>>>(edge_src, edge_dst, rst, bsrc);
    long total_u = (long)N_USER * DIM;
    norm_kernel<<<(int)((total_u + BLK - 1) / BLK), BLK, 0, stream>>>(bsrc, deg_src, total_u);
}

// Round 7
// 711.755 us; speedup vs baseline: 1.9199x; 1.0404x over previous
//
#include <hip/hip_runtime.h>

// Problem constants (match reference)
#define N_USER  500000
#define N_GROUP 100000
#define N_EDGE  5000000
#define DIM     64

#define SCAN_BLOCK 256
#define SCAN_ELEMS 4096            // elements per scan block (16 per thread)
#define PER_THREAD (SCAN_ELEMS / SCAN_BLOCK)

// Multisplit coarse-bucket geometry
#define KD_SHIFT 8                                   // 256 group-keys / coarse bucket
#define KS_SHIFT 10                                  // 1024 user-keys / coarse bucket
#define C_DST ((N_GROUP + (1 << KD_SHIFT) - 1) >> KD_SHIFT)   // 391
#define C_SRC ((N_USER  + (1 << KS_SHIFT) - 1) >> KS_SHIFT)   // 489
#define TILE_A 16384                                 // edges per pass-A block
#define CVT_BLOCKS 1024

typedef unsigned int uint32;
typedef unsigned long long u64;

__device__ inline unsigned short f2bf(float x) {
    uint32 b = __float_as_uint(x);
    uint32 r = (b + 0x7FFFu + ((b >> 16) & 1u)) >> 16;   // round-to-nearest-even
    return (unsigned short)r;
}
__device__ inline float ldt(const float* t, size_t i) { return t[i]; }
__device__ inline float ldt(const unsigned short* t, size_t i) {
    return __uint_as_float((uint32)t[i] << 16);
}

// ---------------------------------------------------------------------------
// Fused prep: blocks [0,gridA) do the coarse LDS histogram (merged with ~270K
// global atomics); blocks [gridA, gridA+CVT_BLOCKS) convert h_user -> bf16.
// ---------------------------------------------------------------------------
__global__ void prep_kernel(const int* __restrict__ src,
                            const int* __restrict__ dst,
                            int* __restrict__ ccd,
                            int* __restrict__ ccs,
                            const float* __restrict__ hin,
                            unsigned short* __restrict__ h16,
                            int gridA) {
    __shared__ int hd[C_DST], hs[C_SRC];
    int tid = threadIdx.x;
    if ((int)blockIdx.x < gridA) {
        long base = (long)blockIdx.x * TILE_A;
        for (int k = tid; k < C_DST; k += blockDim.x) hd[k] = 0;
        for (int k = tid; k < C_SRC; k += blockDim.x) hs[k] = 0;
        __syncthreads();
        for (int i = tid; i < TILE_A; i += blockDim.x) {
            long e = base + i;
            if (e >= N_EDGE) break;
            atomicAdd(&hd[dst[e] >> KD_SHIFT], 1);
            atomicAdd(&hs[src[e] >> KS_SHIFT], 1);
        }
        __syncthreads();
        for (int k = tid; k < C_DST; k += blockDim.x) if (hd[k]) atomicAdd(&ccd[k], hd[k]);
        for (int k = tid; k < C_SRC; k += blockDim.x) if (hs[k]) atomicAdd(&ccs[k], hs[k]);
    } else if (h16) {
        long n4 = (long)N_USER * DIM / 4;
        long stride = (long)CVT_BLOCKS * blockDim.x;
        for (long i = (long)(blockIdx.x - gridA) * blockDim.x + tid; i < n4; i += stride) {
            const float4 v = ((const float4*)hin)[i];
            ushort4 o;
            o.x = f2bf(v.x); o.y = f2bf(v.y); o.z = f2bf(v.z); o.w = f2bf(v.w);
            ((ushort4*)h16)[i] = o;
        }
    }
}

// ---------------------------------------------------------------------------
// Small single-block exclusive scan (n <= 4096): writes coff[0..n], seeds the
// line-padded cursors, and writes the CSR tail sentinel (= total = N_EDGE).
// Replaces scan1+scan2+init_curs+set_tail on the multisplit path.
// ---------------------------------------------------------------------------
#define SS_PT 16
__global__ void small_scan(const int* __restrict__ cnt,
                           int* __restrict__ coff,
                           int* __restrict__ curs,
                           int n,
                           int* __restrict__ tail) {
    __shared__ int tsum[256];
    int tid = threadIdx.x;
    int local[SS_PT];
    int sum = 0;
    int base = tid * SS_PT;
#pragma unroll
    for (int i = 0; i < SS_PT; ++i) {
        int idx = base + i;
        int v = (idx < n) ? cnt[idx] : 0;
        local[i] = sum;
        sum += v;
    }
    tsum[tid] = sum;
    __syncthreads();
    for (int o = 1; o < 256; o <<= 1) {
        int t = (tid >= o) ? tsum[tid - o] : 0;
        __syncthreads();
        tsum[tid] += t;
        __syncthreads();
    }
    int texc = tsum[tid] - sum;
    int total = tsum[255];
#pragma unroll
    for (int i = 0; i < SS_PT; ++i) {
        int idx = base + i;
        if (idx < n) {
            int v = texc + local[i];
            coff[idx] = v;
            curs[idx * 16] = v;
        }
    }
    if (tid == 0) {
        coff[n] = total;
        if (tail) *tail = total;
    }
}

// ---------------------------------------------------------------------------
// Exclusive scan (3 stages) — fallback tiers only.
// ---------------------------------------------------------------------------
__global__ void scan1_kernel(const int* __restrict__ cnt,
                             int* __restrict__ off,
                             int* __restrict__ partial,
                             int n) {
    __shared__ int sh[SCAN_BLOCK];
    int tid = threadIdx.x;
    int tbase = blockIdx.x * SCAN_ELEMS + tid * PER_THREAD;
    int local[PER_THREAD];
    int sum = 0;
#pragma unroll
    for (int i = 0; i < PER_THREAD; ++i) {
        int idx = tbase + i;
        int v = (idx < n) ? cnt[idx] : 0;
        local[i] = sum;
        sum += v;
    }
    sh[tid] = sum;
    __syncthreads();
    for (int o = 1; o < SCAN_BLOCK; o <<= 1) {
        int t = (tid >= o) ? sh[tid - o] : 0;
        __syncthreads();
        sh[tid] += t;
        __syncthreads();
    }
    int texc = sh[tid] - sum;
    int blockTotal = sh[SCAN_BLOCK - 1];
#pragma unroll
    for (int i = 0; i < PER_THREAD; ++i) {
        int idx = tbase + i;
        if (idx < n) off[idx] = local[i] + texc;
    }
    if (tid == 0) partial[blockIdx.x] = blockTotal;
}

__global__ void scan2_kernel(int* __restrict__ partial, int nb,
                             int* __restrict__ off_end) {
    __shared__ int sh[SCAN_BLOCK];
    int tid = threadIdx.x;
    int v = (tid < nb) ? partial[tid] : 0;
    sh[tid] = v;
    __syncthreads();
    for (int o = 1; o < SCAN_BLOCK; o <<= 1) {
        int t = (tid >= o) ? sh[tid - o] : 0;
        __syncthreads();
        sh[tid] += t;
        __syncthreads();
    }
    if (tid < nb) partial[tid] = sh[tid] - v;
    if (tid == 0) *off_end = sh[SCAN_BLOCK - 1];
}

__global__ void scan3_kernel(int* __restrict__ off,
                             const int* __restrict__ partial, int n) {
    int base = blockIdx.x * SCAN_ELEMS;
    int add = partial[blockIdx.x];
    for (int i = threadIdx.x; i < SCAN_ELEMS; i += blockDim.x) {
        int idx = base + i;
        if (idx < n) off[idx] += add;
    }
}

// ---------------------------------------------------------------------------
// Pass A: per-block LDS histogram over coarse buckets, reserve contiguous
// runs via line-padded global cursors, write packed u32 (keylo<<20 | val)
// into private runs -> each 64B line is completed by one block quickly.
// ---------------------------------------------------------------------------
__global__ void passA(const int* __restrict__ src,
                      const int* __restrict__ dst,
                      int* __restrict__ curs_cd,
                      int* __restrict__ curs_cs,
                      uint32* __restrict__ coarse_dst,
                      uint32* __restrict__ coarse_src) {
    __shared__ int hd[C_DST], bd[C_DST], hs[C_SRC], bs[C_SRC];
    int tid = threadIdx.x;
    long base = (long)blockIdx.x * TILE_A;

    for (int c = tid; c < C_DST; c += blockDim.x) hd[c] = 0;
    for (int c = tid; c < C_SRC; c += blockDim.x) hs[c] = 0;
    __syncthreads();

    for (int i = tid; i < TILE_A; i += blockDim.x) {
        long e = base + i;
        if (e >= N_EDGE) break;
        int g = dst[e], u = src[e];
        atomicAdd(&hd[g >> KD_SHIFT], 1);
        atomicAdd(&hs[u >> KS_SHIFT], 1);
    }
    __syncthreads();

    for (int c = tid; c < C_DST; c += blockDim.x) {
        int n = hd[c];
        bd[c] = n ? atomicAdd(&curs_cd[c * 16], n) : 0;
        hd[c] = 0;
    }
    for (int c = tid; c < C_SRC; c += blockDim.x) {
        int n = hs[c];
        bs[c] = n ? atomicAdd(&curs_cs[c * 16], n) : 0;
        hs[c] = 0;
    }
    __syncthreads();

    for (int i = tid; i < TILE_A; i += blockDim.x) {
        long e = base + i;
        if (e >= N_EDGE) break;
        int g = dst[e], u = src[e];
        int cd = g >> KD_SHIFT;
        int pd = atomicAdd(&hd[cd], 1);
        coarse_dst[(size_t)bd[cd] + pd] =
            ((uint32)(g & ((1 << KD_SHIFT) - 1)) << 20) | (uint32)u;
        int cs = u >> KS_SHIFT;
        int ps = atomicAdd(&hs[cs], 1);
        coarse_src[(size_t)bs[cs] + ps] =
            ((uint32)(u & ((1 << KS_SHIFT) - 1)) << 20) | (uint32)g;
    }
}

// ---------------------------------------------------------------------------
// Pass B: one workgroup per coarse bucket. LDS fine-histogram of the <=2^SHIFT
// key range, LDS exclusive scan -> writes the global off[] slice, then
// scatters values to final slots with LDS cursors (no global cur[] atomics).
// ---------------------------------------------------------------------------
template <int SHIFT>
__global__ void passB_t(const uint32* __restrict__ coarse,
                        const int* __restrict__ coarse_off,
                        int* __restrict__ off,
                        int* __restrict__ bucket,
                        int n) {
    const int NK = 1 << SHIFT;
    const int PT = NK / 256;
    __shared__ int hist[NK];
    __shared__ int tsum[256];
    int tid = threadIdx.x;
    int c = blockIdx.x;
    int lo = c << SHIFT;
    int beg = coarse_off[c], end = coarse_off[c + 1];

    for (int k = tid; k < NK; k += 256) hist[k] = 0;
    __syncthreads();

    for (int i = beg + tid; i < end; i += 256) {
        uint32 kv = __builtin_nontemporal_load(&coarse[i]);
        atomicAdd(&hist[kv >> 20], 1);
    }
    __syncthreads();

    int local[PT];
    int sum = 0;
#pragma unroll
    for (int i = 0; i < PT; ++i) {
        int v = hist[tid * PT + i];
        local[i] = sum;
        sum += v;
    }
    tsum[tid] = sum;
    __syncthreads();
    for (int o = 1; o < 256; o <<= 1) {
        int t = (tid >= o) ? tsum[tid - o] : 0;
        __syncthreads();
        tsum[tid] += t;
        __syncthreads();
    }
    int texc = tsum[tid] - sum;
    __syncthreads();
#pragma unroll
    for (int i = 0; i < PT; ++i) {
        int k = tid * PT + i;
        int excl = texc + local[i];
        hist[k] = excl;                            // cursor seed
        if (lo + k < n) off[lo + k] = beg + excl;  // global CSR offsets
    }
    __syncthreads();

    for (int i = beg + tid; i < end; i += 256) {
        uint32 kv = __builtin_nontemporal_load(&coarse[i]);
        int p = atomicAdd(&hist[kv >> 20], 1);
        bucket[beg + p] = (int)(kv & 0xFFFFFu);
    }
}

// ---------------------------------------------------------------------------
// Fallback-tier kernels.
// ---------------------------------------------------------------------------
__global__ void hist_kernel(const int* __restrict__ src,
                            const int* __restrict__ dst,
                            int* __restrict__ cnt_src,
                            int* __restrict__ cnt_dst) {
    int e = blockIdx.x * blockDim.x + threadIdx.x;
    if (e < N_EDGE) {
        atomicAdd(&cnt_src[src[e]], 1);
        atomicAdd(&cnt_dst[dst[e]], 1);
    }
}

__global__ void fill_both(const int* __restrict__ src,
                          const int* __restrict__ dst,
                          const int* __restrict__ off_src,
                          const int* __restrict__ off_dst,
                          int* __restrict__ cur_src,
                          int* __restrict__ cur_dst,
                          int* __restrict__ bucket_src,
                          int* __restrict__ bucket_dst) {
    int e = blockIdx.x * blockDim.x + threadIdx.x;
    if (e < N_EDGE) {
        int u = src[e];
        int g = dst[e];
        int p = atomicAdd(&cur_src[u], 1);
        bucket_src[off_src[u] + p] = g;
        int q = atomicAdd(&cur_dst[g], 1);
        bucket_dst[off_dst[g] + q] = u;
    }
}

__global__ void fill_one(const int* __restrict__ key,
                         const int* __restrict__ val,
                         const int* __restrict__ off,
                         int* __restrict__ cur,
                         int* __restrict__ bucket) {
    int e = blockIdx.x * blockDim.x + threadIdx.x;
    if (e < N_EDGE) {
        int k = key[e];
        int p = atomicAdd(&cur[k], 1);
        bucket[off[k] + p] = val[e];
    }
}

__global__ void cvt_bf16(const float* __restrict__ in,
                         unsigned short* __restrict__ out, long n4) {
    long i = (long)blockIdx.x * blockDim.x + threadIdx.x;
    if (i >= n4) return;
    const float4 v = ((const float4*)in)[i];
    ushort4 o;
    o.x = f2bf(v.x); o.y = f2bf(v.y); o.z = f2bf(v.z); o.w = f2bf(v.w);
    ((ushort4*)out)[i] = o;
}

// ---------------------------------------------------------------------------
// Gather v2: one wave per row, lane = dim. Per 64-edge window each lane loads
// ONE bucket entry (coalesced), then __shfl broadcasts per-edge row ids --
// removes the per-edge 64-lane broadcast loads and most tail clamp logic.
// U = unroll/accumulator depth (8 for fwd deg~50, 4 for bwd deg~10).
// ---------------------------------------------------------------------------
template <int NROW, bool NT, int U, typename T>
__global__ void gather_kernel(const int* __restrict__ off,
                              const int* __restrict__ bucket,
                              const T* __restrict__ table,
                              float* __restrict__ out,
                              unsigned short* __restrict__ out16) {
    int wid = (blockIdx.x * blockDim.x + threadIdx.x) >> 6;
    int lane = threadIdx.x & 63;
    if (wid >= NROW) return;
    int beg = off[wid], end = off[wid + 1];

    float a[U];
#pragma unroll
    for (int j = 0; j < U; ++j) a[j] = 0.0f;

    for (int b = beg; b < end; b += 64) {
        int navail = min(64, end - b);
        int sv = bucket[b + (lane < navail ? lane : 0)];
        int k = 0;
        for (; k + U <= navail; k += U) {
#pragma unroll
            for (int j = 0; j < U; ++j) {
                int s = __shfl(sv, k + j);
                a[j] += ldt(table, (size_t)s * DIM + lane);
            }
        }
        if (k < navail) {
#pragma unroll
            for (int j = 0; j < U; ++j) {
                int kk = k + j;
                int s = __shfl(sv, kk < navail ? kk : navail - 1);
                float w = (kk < navail) ? 1.0f : 0.0f;
                a[j] += w * ldt(table, (size_t)s * DIM + lane);
            }
        }
    }
    float acc = 0.0f;
#pragma unroll
    for (int j = 0; j < U; ++j) acc += a[j];
    float inv = 1.0f / fmaxf((float)(end - beg), 1.0f);
    float r = acc * inv;
    if (NT) {
        __builtin_nontemporal_store(r, &out[(size_t)wid * DIM + lane]);
    } else {
        out[(size_t)wid * DIM + lane] = r;
    }
    if (out16) out16[(size_t)wid * DIM + lane] = f2bf(r);
}

// ===========================================================================
// Last-resort fallback (atomic path).
// ===========================================================================
__global__ void deg_kernel(const int* __restrict__ src,
                           const int* __restrict__ dst,
                           float* __restrict__ deg_src,
                           float* __restrict__ deg_dst) {
    int e = blockIdx.x * blockDim.x + threadIdx.x;
    if (e < N_EDGE) {
        unsafeAtomicAdd(&deg_src[src[e]], 1.0f);
        unsafeAtomicAdd(&deg_dst[dst[e]], 1.0f);
    }
}

__global__ void scatter_fwd(const int* __restrict__ src,
                            const int* __restrict__ dst,
                            const float* __restrict__ h_user,
                            float* __restrict__ rst) {
    long idx = (long)blockIdx.x * blockDim.x + threadIdx.x;
    if (idx >= (long)N_EDGE * DIM) return;
    int e = (int)(idx >> 6), d = (int)(idx & 63);
    unsafeAtomicAdd(&rst[(long)dst[e] * DIM + d], h_user[(long)src[e] * DIM + d]);
}

__global__ void norm_kernel(float* __restrict__ x,
                            const float* __restrict__ deg, long total) {
    long idx = (long)blockIdx.x * blockDim.x + threadIdx.x;
    if (idx >= total) return;
    float dg = fmaxf(deg[idx >> 6], 1.0f);
    x[idx] *= (1.0f / dg);
}

__global__ void scatter_bwd(const int* __restrict__ src,
                            const int* __restrict__ dst,
                            const float* __restrict__ rst,
                            float* __restrict__ bsrc) {
    long idx = (long)blockIdx.x * blockDim.x + threadIdx.x;
    if (idx >= (long)N_EDGE * DIM) return;
    int e = (int)(idx >> 6), d = (int)(idx & 63);
    unsafeAtomicAdd(&bsrc[(long)src[e] * DIM + d], rst[(long)dst[e] * DIM + d]);
}

extern "C" void kernel_launch(void* const* d_in, const int* in_sizes, int n_in,
                              void* d_out, int out_size, void* d_ws, size_t ws_size,
                              hipStream_t stream) {
    const float* h_user   = (const float*)d_in[0];
    const int*   edge_src = (const int*)d_in[2];
    const int*   edge_dst = (const int*)d_in[3];

    float* bsrc = (float*)d_out;                   // [N_USER, DIM]
    float* rst  = bsrc + (size_t)N_USER * DIM;     // [N_GROUP, DIM]

    const int BLK = 256;
    const int grid_e = (N_EDGE + BLK - 1) / BLK;

    // ---- scratch layout (header kept fallback-compatible) ---------------
    int* ws      = (int*)d_ws;
    int* cnt_dst = ws;                              // N_GROUP        (fallback only)
    int* off_dst = cnt_dst + N_GROUP;               // N_GROUP + 1
    int* cnt_src = off_dst + N_GROUP + 1;           // N_USER         (fallback only)
    int* off_src = cnt_src + N_USER;                // N_USER + 1
    int* cur_dst = off_src + N_USER + 1;            // N_GROUP        (fallback only)
    int* cur_src = cur_dst + N_GROUP;               // N_USER         (fallback only)
    int* partial = cur_src + N_USER;                // 256
    int* bucket_dst = partial + 256;                // N_EDGE (by dst -> stores src)
    int* bucket_src = bucket_dst + N_EDGE;          // N_EDGE (by src -> stores dst)
    unsigned short* r16 = (unsigned short*)(bucket_src + N_EDGE);  // N_GROUP*DIM
    unsigned short* h16 = r16 + (size_t)N_GROUP * DIM;             // N_USER*DIM
    // multisplit extras (8B-aligned tail)
    size_t tail = ((size_t)((char*)(h16 + (size_t)N_USER * DIM) - (char*)d_ws) + 7) & ~(size_t)7;
    int* curs_cd = (int*)((char*)d_ws + tail);      // C_DST * 16 (line-padded)
    int* curs_cs = curs_cd + C_DST * 16;            // C_SRC * 16
    int* ccnt_d  = curs_cs + C_SRC * 16;            // C_DST  coarse counts
    int* ccnt_s  = ccnt_d + C_DST;                  // C_SRC  coarse counts
    int* coff_d  = ccnt_s + C_SRC;                  // C_DST + 1
    int* coff_s  = coff_d + C_DST + 1;              // C_SRC + 1
    size_t tail2 = ((size_t)((char*)(coff_s + C_SRC + 1) - (char*)d_ws) + 7) & ~(size_t)7;
    uint32* coarse_dst = (uint32*)((char*)d_ws + tail2);  // N_EDGE u32 (packed)
    uint32* coarse_src = coarse_dst + N_EDGE;             // N_EDGE u32 (packed)

    size_t need_csr1 = (size_t)((bucket_dst + N_EDGE) - ws) * sizeof(int);
    size_t need_csr2 = (size_t)((bucket_src + N_EDGE) - ws) * sizeof(int);
    size_t need_r16  = need_csr2 + (size_t)N_GROUP * DIM * 2;
    size_t need_full = need_r16 + (size_t)N_USER * DIM * 2;
    size_t need_ms   = (size_t)((char*)(coarse_src + N_EDGE) - (char*)d_ws);

    int nb_dst = (N_GROUP + SCAN_ELEMS - 1) / SCAN_ELEMS;
    int nb_src = (N_USER + SCAN_ELEMS - 1) / SCAN_ELEMS;

    if (ws_size >= need_ms) {
        // ---- multisplit path ---------------------------------------------
        bool use_h16 = (ws_size >= need_full);
        bool use_r16 = (ws_size >= need_r16);

        // Zero only the coarse counters (tiny, contiguous).
        hipMemsetAsync(ccnt_d, 0, (size_t)(C_DST + C_SRC) * sizeof(int), stream);

        int gridA = (N_EDGE + TILE_A - 1) / TILE_A;   // 306
        int gridP = gridA + (use_h16 ? CVT_BLOCKS : 0);
        prep_kernel<<<gridP, BLK, 0, stream>>>(edge_src, edge_dst, ccnt_d, ccnt_s,
                                               h_user, use_h16 ? h16 : nullptr, gridA);

        small_scan<<<1, 256, 0, stream>>>(ccnt_d, coff_d, curs_cd, C_DST, off_dst + N_GROUP);
        small_scan<<<1, 256, 0, stream>>>(ccnt_s, coff_s, curs_cs, C_SRC, off_src + N_USER);

        passA<<<gridA, BLK, 0, stream>>>(edge_src, edge_dst,
                                         curs_cd, curs_cs, coarse_dst, coarse_src);

        passB_t<KD_SHIFT><<<C_DST, 256, 0, stream>>>(coarse_dst, coff_d,
                                                     off_dst, bucket_dst, N_GROUP);
        passB_t<KS_SHIFT><<<C_SRC, 256, 0, stream>>>(coarse_src, coff_s,
                                                     off_src, bucket_src, N_USER);

        unsigned short* r16p = use_r16 ? r16 : (unsigned short*)nullptr;
        if (use_h16) {
            gather_kernel<N_GROUP, false, 8, unsigned short>
                <<<(N_GROUP * 64 + BLK - 1) / BLK, BLK, 0, stream>>>(
                    off_dst, bucket_dst, h16, rst, r16p);
        } else {
            gather_kernel<N_GROUP, false, 8, float>
                <<<(N_GROUP * 64 + BLK - 1) / BLK, BLK, 0, stream>>>(
                    off_dst, bucket_dst, h_user, rst, r16p);
        }
        if (use_r16) {
            gather_kernel<N_USER, true, 4, unsigned short>
                <<<(int)(((size_t)N_USER * 64 + BLK - 1) / BLK), BLK, 0, stream>>>(
                    off_src, bucket_src, r16, bsrc, nullptr);
        } else {
            gather_kernel<N_USER, true, 4, float>
                <<<(int)(((size_t)N_USER * 64 + BLK - 1) / BLK), BLK, 0, stream>>>(
                    off_src, bucket_src, rst, bsrc, nullptr);
        }
        return;
    }

    if (ws_size >= need_csr2) {
        // ---- fallback: hist+scan+fused fill (round-3 structure) ---------
        bool use_h16 = (ws_size >= need_full);
        bool use_r16 = (ws_size >= need_r16);

        hipMemsetAsync(d_ws, 0, (size_t)(partial - ws) * sizeof(int), stream);

        if (use_h16) {
            long n4 = (long)N_USER * DIM / 4;
            cvt_bf16<<<(int)((n4 + BLK - 1) / BLK), BLK, 0, stream>>>(h_user, h16, n4);
        }

        hist_kernel<<<grid_e, BLK, 0, stream>>>(edge_src, edge_dst, cnt_src, cnt_dst);

        scan1_kernel<<<nb_dst, SCAN_BLOCK, 0, stream>>>(cnt_dst, off_dst, partial, N_GROUP);
        scan2_kernel<<<1, SCAN_BLOCK, 0, stream>>>(partial, nb_dst, off_dst + N_GROUP);
        scan3_kernel<<<nb_dst, SCAN_BLOCK, 0, stream>>>(off_dst, partial, N_GROUP);

        scan1_kernel<<<nb_src, SCAN_BLOCK, 0, stream>>>(cnt_src, off_src, partial, N_USER);
        scan2_kernel<<<1, SCAN_BLOCK, 0, stream>>>(partial, nb_src, off_src + N_USER);
        scan3_kernel<<<nb_src, SCAN_BLOCK, 0, stream>>>(off_src, partial, N_USER);

        fill_both<<<grid_e, BLK, 0, stream>>>(
            edge_src, edge_dst, off_src, off_dst,
            cur_src, cur_dst, bucket_src, bucket_dst);

        unsigned short* r16p = use_r16 ? r16 : (unsigned short*)nullptr;
        if (use_h16) {
            gather_kernel<N_GROUP, false, 8, unsigned short>
                <<<(N_GROUP * 64 + BLK - 1) / BLK, BLK, 0, stream>>>(
                    off_dst, bucket_dst, h16, rst, r16p);
        } else {
            gather_kernel<N_GROUP, false, 8, float>
                <<<(N_GROUP * 64 + BLK - 1) / BLK, BLK, 0, stream>>>(
                    off_dst, bucket_dst, h_user, rst, r16p);
        }
        if (use_r16) {
            gather_kernel<N_USER, true, 4, unsigned short>
                <<<(int)(((size_t)N_USER * 64 + BLK - 1) / BLK), BLK, 0, stream>>>(
                    off_src, bucket_src, r16, bsrc, nullptr);
        } else {
            gather_kernel<N_USER, true, 4, float>
                <<<(int)(((size_t)N_USER * 64 + BLK - 1) / BLK), BLK, 0, stream>>>(
                    off_src, bucket_src, rst, bsrc, nullptr);
        }
        return;
    }

    if (ws_size >= need_csr1) {
        // Sequential single-bucket path (f32 gathers).
        hipMemsetAsync(d_ws, 0, (size_t)(partial - ws) * sizeof(int), stream);
        hist_kernel<<<grid_e, BLK, 0, stream>>>(edge_src, edge_dst, cnt_src, cnt_dst);

        scan1_kernel<<<nb_dst, SCAN_BLOCK, 0, stream>>>(cnt_dst, off_dst, partial, N_GROUP);
        scan2_kernel<<<1, SCAN_BLOCK, 0, stream>>>(partial, nb_dst, off_dst + N_GROUP);
        scan3_kernel<<<nb_dst, SCAN_BLOCK, 0, stream>>>(off_dst, partial, N_GROUP);

        scan1_kernel<<<nb_src, SCAN_BLOCK, 0, stream>>>(cnt_src, off_src, partial, N_USER);
        scan2_kernel<<<1, SCAN_BLOCK, 0, stream>>>(partial, nb_src, off_src + N_USER);
        scan3_kernel<<<nb_src, SCAN_BLOCK, 0, stream>>>(off_src, partial, N_USER);

        fill_one<<<grid_e, BLK, 0, stream>>>(edge_dst, edge_src, off_dst, cur_dst, bucket_dst);
        gather_kernel<N_GROUP, false, 8, float>
            <<<(N_GROUP * 64 + BLK - 1) / BLK, BLK, 0, stream>>>(
                off_dst, bucket_dst, h_user, rst, nullptr);

        fill_one<<<grid_e, BLK, 0, stream>>>(edge_src, edge_dst, off_src, cur_src, bucket_dst);
        gather_kernel<N_USER, true, 4, float>
            <<<(int)(((size_t)N_USER * 64 + BLK - 1) / BLK), BLK, 0, stream>>>(
                off_src, bucket_dst, rst, bsrc, nullptr);
        return;
    }

    // ---- Fallback: atomic path ------------------------------------------
    float* deg_dst = (float*)d_ws;
    float* deg_src = deg_dst + N_GROUP;
    hipMemsetAsync(d_out, 0, (size_t)(N_USER + N_GROUP) * DIM * sizeof(float), stream);
    hipMemsetAsync(d_ws, 0, (size_t)(N_USER + N_GROUP) * sizeof(float), stream);

    deg_kernel<<<grid_e, BLK, 0, stream>>>(edge_src, edge_dst, deg_src, deg_dst);

    long total_ed = (long)N_EDGE * DIM;
    int grid_ed = (int)((total_ed + BLK - 1) / BLK);
    scatter_fwd<<<grid_ed, BLK, 0, stream>>>(edge_src, edge_dst, h_user, rst);
    long total_g = (long)N_GROUP * DIM;
    norm_kernel<<<(int)((total_g + BLK - 1) / BLK), BLK, 0, stream>>>(rst, deg_dst, total_g);
    scatter_bwd<<<grid_ed, BLK, 0, stream>>>(edge_src, edge_dst, rst, bsrc);
    long total_u = (long)N_USER * DIM;
    norm_kernel<<<(int)((total_u + BLK - 1) / BLK), BLK, 0, stream>>>(bsrc, deg_src, total_u);
}

// Round 8
// 597.877 us; speedup vs baseline: 2.2856x; 1.1905x over previous
//
#include <hip/hip_runtime.h>

// Problem constants (match reference)
#define N_USER  500000
#define N_GROUP 100000
#define N_EDGE  5000000
#define DIM     64

#define SCAN_BLOCK 256
#define SCAN_ELEMS 4096            // elements per scan block (16 per thread)
#define PER_THREAD (SCAN_ELEMS / SCAN_BLOCK)

// Multisplit coarse-bucket geometry (sized so one block's bucket fits LDS and
// grid ~3-4 blocks/CU for balance)
#define KD_SHIFT 7                                   // 128 group-keys / coarse bucket
#define KS_SHIFT 9                                   // 512 user-keys / coarse bucket
#define C_DST ((N_GROUP + (1 << KD_SHIFT) - 1) >> KD_SHIFT)   // 782
#define C_SRC ((N_USER  + (1 << KS_SHIFT) - 1) >> KS_SHIFT)   // 977
#define TILE_A 16384                                 // edges per pass-A block
#define CVT_BLOCKS 1024
// LDS staging caps: mean + ~16 sigma (dst mean 6400 sd 80; src mean 5120 sd 72)
#define CAP_D 7680
#define CAP_S 6272

typedef unsigned int uint32;

__device__ inline unsigned short f2bf(float x) {
    uint32 b = __float_as_uint(x);
    uint32 r = (b + 0x7FFFu + ((b >> 16) & 1u)) >> 16;   // round-to-nearest-even
    return (unsigned short)r;
}
__device__ inline float ldt(const float* t, size_t i) { return t[i]; }
__device__ inline float ldt(const unsigned short* t, size_t i) {
    return __uint_as_float((uint32)t[i] << 16);
}

// ---------------------------------------------------------------------------
// Fused prep: blocks [0,gridA) do the coarse LDS histogram (merged with small
// global atomics); blocks [gridA, gridA+CVT_BLOCKS) convert h_user -> bf16.
// ---------------------------------------------------------------------------
__global__ void prep_kernel(const int* __restrict__ src,
                            const int* __restrict__ dst,
                            int* __restrict__ ccd,
                            int* __restrict__ ccs,
                            const float* __restrict__ hin,
                            unsigned short* __restrict__ h16,
                            int gridA) {
    __shared__ int hd[C_DST], hs[C_SRC];
    int tid = threadIdx.x;
    if ((int)blockIdx.x < gridA) {
        long base = (long)blockIdx.x * TILE_A;
        for (int k = tid; k < C_DST; k += blockDim.x) hd[k] = 0;
        for (int k = tid; k < C_SRC; k += blockDim.x) hs[k] = 0;
        __syncthreads();
        for (int i = tid; i < TILE_A; i += blockDim.x) {
            long e = base + i;
            if (e >= N_EDGE) break;
            atomicAdd(&hd[dst[e] >> KD_SHIFT], 1);
            atomicAdd(&hs[src[e] >> KS_SHIFT], 1);
        }
        __syncthreads();
        for (int k = tid; k < C_DST; k += blockDim.x) if (hd[k]) atomicAdd(&ccd[k], hd[k]);
        for (int k = tid; k < C_SRC; k += blockDim.x) if (hs[k]) atomicAdd(&ccs[k], hs[k]);
    } else if (h16) {
        long n4 = (long)N_USER * DIM / 4;
        long stride = (long)CVT_BLOCKS * blockDim.x;
        for (long i = (long)(blockIdx.x - gridA) * blockDim.x + tid; i < n4; i += stride) {
            const float4 v = ((const float4*)hin)[i];
            ushort4 o;
            o.x = f2bf(v.x); o.y = f2bf(v.y); o.z = f2bf(v.z); o.w = f2bf(v.w);
            ((ushort4*)h16)[i] = o;
        }
    }
}

// ---------------------------------------------------------------------------
// Small single-block exclusive scan (n <= 4096): writes coff[0..n] and seeds
// the line-padded cursors.
// ---------------------------------------------------------------------------
#define SS_PT 16
__global__ void small_scan(const int* __restrict__ cnt,
                           int* __restrict__ coff,
                           int* __restrict__ curs,
                           int n,
                           int* __restrict__ tail) {
    __shared__ int tsum[256];
    int tid = threadIdx.x;
    int local[SS_PT];
    int sum = 0;
    int base = tid * SS_PT;
#pragma unroll
    for (int i = 0; i < SS_PT; ++i) {
        int idx = base + i;
        int v = (idx < n) ? cnt[idx] : 0;
        local[i] = sum;
        sum += v;
    }
    tsum[tid] = sum;
    __syncthreads();
    for (int o = 1; o < 256; o <<= 1) {
        int t = (tid >= o) ? tsum[tid - o] : 0;
        __syncthreads();
        tsum[tid] += t;
        __syncthreads();
    }
    int texc = tsum[tid] - sum;
    int total = tsum[255];
#pragma unroll
    for (int i = 0; i < SS_PT; ++i) {
        int idx = base + i;
        if (idx < n) {
            int v = texc + local[i];
            coff[idx] = v;
            curs[idx * 16] = v;
        }
    }
    if (tid == 0) {
        coff[n] = total;
        if (tail) *tail = total;
    }
}

// ---------------------------------------------------------------------------
// Exclusive scan (3 stages) — fallback tiers only.
// ---------------------------------------------------------------------------
__global__ void scan1_kernel(const int* __restrict__ cnt,
                             int* __restrict__ off,
                             int* __restrict__ partial,
                             int n) {
    __shared__ int sh[SCAN_BLOCK];
    int tid = threadIdx.x;
    int tbase = blockIdx.x * SCAN_ELEMS + tid * PER_THREAD;
    int local[PER_THREAD];
    int sum = 0;
#pragma unroll
    for (int i = 0; i < PER_THREAD; ++i) {
        int idx = tbase + i;
        int v = (idx < n) ? cnt[idx] : 0;
        local[i] = sum;
        sum += v;
    }
    sh[tid] = sum;
    __syncthreads();
    for (int o = 1; o < SCAN_BLOCK; o <<= 1) {
        int t = (tid >= o) ? sh[tid - o] : 0;
        __syncthreads();
        sh[tid] += t;
        __syncthreads();
    }
    int texc = sh[tid] - sum;
    int blockTotal = sh[SCAN_BLOCK - 1];
#pragma unroll
    for (int i = 0; i < PER_THREAD; ++i) {
        int idx = tbase + i;
        if (idx < n) off[idx] = local[i] + texc;
    }
    if (tid == 0) partial[blockIdx.x] = blockTotal;
}

__global__ void scan2_kernel(int* __restrict__ partial, int nb,
                             int* __restrict__ off_end) {
    __shared__ int sh[SCAN_BLOCK];
    int tid = threadIdx.x;
    int v = (tid < nb) ? partial[tid] : 0;
    sh[tid] = v;
    __syncthreads();
    for (int o = 1; o < SCAN_BLOCK; o <<= 1) {
        int t = (tid >= o) ? sh[tid - o] : 0;
        __syncthreads();
        sh[tid] += t;
        __syncthreads();
    }
    if (tid < nb) partial[tid] = sh[tid] - v;
    if (tid == 0) *off_end = sh[SCAN_BLOCK - 1];
}

__global__ void scan3_kernel(int* __restrict__ off,
                             const int* __restrict__ partial, int n) {
    int base = blockIdx.x * SCAN_ELEMS;
    int add = partial[blockIdx.x];
    for (int i = threadIdx.x; i < SCAN_ELEMS; i += blockDim.x) {
        int idx = base + i;
        if (idx < n) off[idx] += add;
    }
}

// ---------------------------------------------------------------------------
// Pass A: per-block LDS histogram over coarse buckets, reserve contiguous
// runs via line-padded global cursors, write packed u32 (keylo<<20 | val)
// into private runs -> each 64B line is completed by one block quickly.
// ---------------------------------------------------------------------------
__global__ void passA(const int* __restrict__ src,
                      const int* __restrict__ dst,
                      int* __restrict__ curs_cd,
                      int* __restrict__ curs_cs,
                      uint32* __restrict__ coarse_dst,
                      uint32* __restrict__ coarse_src) {
    __shared__ int hd[C_DST], bd[C_DST], hs[C_SRC], bs[C_SRC];
    int tid = threadIdx.x;
    long base = (long)blockIdx.x * TILE_A;

    for (int c = tid; c < C_DST; c += blockDim.x) hd[c] = 0;
    for (int c = tid; c < C_SRC; c += blockDim.x) hs[c] = 0;
    __syncthreads();

    for (int i = tid; i < TILE_A; i += blockDim.x) {
        long e = base + i;
        if (e >= N_EDGE) break;
        int g = dst[e], u = src[e];
        atomicAdd(&hd[g >> KD_SHIFT], 1);
        atomicAdd(&hs[u >> KS_SHIFT], 1);
    }
    __syncthreads();

    for (int c = tid; c < C_DST; c += blockDim.x) {
        int n = hd[c];
        bd[c] = n ? atomicAdd(&curs_cd[c * 16], n) : 0;
        hd[c] = 0;
    }
    for (int c = tid; c < C_SRC; c += blockDim.x) {
        int n = hs[c];
        bs[c] = n ? atomicAdd(&curs_cs[c * 16], n) : 0;
        hs[c] = 0;
    }
    __syncthreads();

    for (int i = tid; i < TILE_A; i += blockDim.x) {
        long e = base + i;
        if (e >= N_EDGE) break;
        int g = dst[e], u = src[e];
        int cd = g >> KD_SHIFT;
        int pd = atomicAdd(&hd[cd], 1);
        coarse_dst[(size_t)bd[cd] + pd] =
            ((uint32)(g & ((1 << KD_SHIFT) - 1)) << 20) | (uint32)u;
        int cs = u >> KS_SHIFT;
        int ps = atomicAdd(&hs[cs], 1);
        coarse_src[(size_t)bs[cs] + ps] =
            ((uint32)(u & ((1 << KS_SHIFT) - 1)) << 20) | (uint32)g;
    }
}

// ---------------------------------------------------------------------------
// Fused sort+gather: one 512-thread block per coarse bucket. Builds the
// fine-sorted adjacency of its <=2^SHIFT keys entirely in LDS (hist -> scan
// -> place), then 8 waves gather rows directly from LDS (per edge: one
// broadcast ds_read + one table row load). No global bucket/off arrays.
// Overflow beyond CAP (statistically ~impossible) handled by a global scan.
// ---------------------------------------------------------------------------
template <int SHIFT, int CAP, int U, bool NT, typename T>
__global__ __launch_bounds__(512) void sortgather(
    const uint32* __restrict__ coarse,
    const int* __restrict__ coarse_off,
    const T* __restrict__ table,
    float* __restrict__ out,
    unsigned short* __restrict__ out16,
    int n) {
    const int NK = 1 << SHIFT;
    __shared__ int vals[CAP];
    __shared__ int hist[NK];   // counts -> inclusive sums
    __shared__ int cur[NK];    // placement cursors
    int tid = threadIdx.x;
    int c = blockIdx.x;
    int lo_g = c << SHIFT;
    int beg = coarse_off[c], end = coarse_off[c + 1];
    int cnt = end - beg;
    int stg = min(cnt, CAP);

    for (int k = tid; k < NK; k += 512) hist[k] = 0;
    __syncthreads();

    for (int i = tid; i < stg; i += 512) {
        uint32 kv = coarse[beg + i];
        atomicAdd(&hist[kv >> 20], 1);
    }
    __syncthreads();

    // inclusive scan over NK bins (all threads reach the barriers)
    for (int o = 1; o < NK; o <<= 1) {
        int t = (tid < NK && tid >= o) ? hist[tid - o] : 0;
        __syncthreads();
        if (tid < NK) hist[tid] += t;
        __syncthreads();
    }
    if (tid < NK) cur[tid] = (tid == 0) ? 0 : hist[tid - 1];
    __syncthreads();

    for (int i = tid; i < stg; i += 512) {
        uint32 kv = coarse[beg + i];
        int p = atomicAdd(&cur[kv >> 20], 1);
        vals[p] = (int)(kv & 0xFFFFFu);
    }
    __syncthreads();

    int wv = tid >> 6, lane = tid & 63;
    for (int r = wv; r < NK; r += 8) {
        int row = lo_g + r;
        if (row >= n) break;             // rows ascend per wave
        int lo = (r == 0) ? 0 : hist[r - 1];
        int hi = hist[r];
        float a[U];
#pragma unroll
        for (int j = 0; j < U; ++j) a[j] = 0.0f;
        int e = lo;
        for (; e + U <= hi; e += U) {
#pragma unroll
            for (int j = 0; j < U; ++j) {
                int s = vals[e + j];
                a[j] += ldt(table, (size_t)s * DIM + lane);
            }
        }
        for (; e < hi; ++e) {
            int s = vals[e];
            a[0] += ldt(table, (size_t)s * DIM + lane);
        }
        int deg = hi - lo;
        if (stg < cnt) {                 // overflow scan (rare)
            for (int i = beg + stg; i < end; ++i) {
                uint32 kv = coarse[i];
                if ((int)(kv >> 20) == r) {
                    a[0] += ldt(table, (size_t)(kv & 0xFFFFFu) * DIM + lane);
                    ++deg;
                }
            }
        }
        float acc = 0.0f;
#pragma unroll
        for (int j = 0; j < U; ++j) acc += a[j];
        float rv = acc / fmaxf((float)deg, 1.0f);
        size_t oidx = (size_t)row * DIM + lane;
        if (NT) __builtin_nontemporal_store(rv, &out[oidx]);
        else out[oidx] = rv;
        if (out16) out16[oidx] = f2bf(rv);
    }
}

// ---------------------------------------------------------------------------
// Fallback-tier kernels.
// ---------------------------------------------------------------------------
__global__ void hist_kernel(const int* __restrict__ src,
                            const int* __restrict__ dst,
                            int* __restrict__ cnt_src,
                            int* __restrict__ cnt_dst) {
    int e = blockIdx.x * blockDim.x + threadIdx.x;
    if (e < N_EDGE) {
        atomicAdd(&cnt_src[src[e]], 1);
        atomicAdd(&cnt_dst[dst[e]], 1);
    }
}

__global__ void fill_both(const int* __restrict__ src,
                          const int* __restrict__ dst,
                          const int* __restrict__ off_src,
                          const int* __restrict__ off_dst,
                          int* __restrict__ cur_src,
                          int* __restrict__ cur_dst,
                          int* __restrict__ bucket_src,
                          int* __restrict__ bucket_dst) {
    int e = blockIdx.x * blockDim.x + threadIdx.x;
    if (e < N_EDGE) {
        int u = src[e];
        int g = dst[e];
        int p = atomicAdd(&cur_src[u], 1);
        bucket_src[off_src[u] + p] = g;
        int q = atomicAdd(&cur_dst[g], 1);
        bucket_dst[off_dst[g] + q] = u;
    }
}

__global__ void fill_one(const int* __restrict__ key,
                         const int* __restrict__ val,
                         const int* __restrict__ off,
                         int* __restrict__ cur,
                         int* __restrict__ bucket) {
    int e = blockIdx.x * blockDim.x + threadIdx.x;
    if (e < N_EDGE) {
        int k = key[e];
        int p = atomicAdd(&cur[k], 1);
        bucket[off[k] + p] = val[e];
    }
}

__global__ void cvt_bf16(const float* __restrict__ in,
                         unsigned short* __restrict__ out, long n4) {
    long i = (long)blockIdx.x * blockDim.x + threadIdx.x;
    if (i >= n4) return;
    const float4 v = ((const float4*)in)[i];
    ushort4 o;
    o.x = f2bf(v.x); o.y = f2bf(v.y); o.z = f2bf(v.z); o.w = f2bf(v.w);
    ((ushort4*)out)[i] = o;
}

// Gather (fallback tiers): one wave per row, window load + shfl broadcast.
template <int NROW, bool NT, int U, typename T>
__global__ void gather_kernel(const int* __restrict__ off,
                              const int* __restrict__ bucket,
                              const T* __restrict__ table,
                              float* __restrict__ out,
                              unsigned short* __restrict__ out16) {
    int wid = (blockIdx.x * blockDim.x + threadIdx.x) >> 6;
    int lane = threadIdx.x & 63;
    if (wid >= NROW) return;
    int beg = off[wid], end = off[wid + 1];

    float a[U];
#pragma unroll
    for (int j = 0; j < U; ++j) a[j] = 0.0f;

    for (int b = beg; b < end; b += 64) {
        int navail = min(64, end - b);
        int sv = bucket[b + (lane < navail ? lane : 0)];
        int k = 0;
        for (; k + U <= navail; k += U) {
#pragma unroll
            for (int j = 0; j < U; ++j) {
                int s = __shfl(sv, k + j);
                a[j] += ldt(table, (size_t)s * DIM + lane);
            }
        }
        if (k < navail) {
#pragma unroll
            for (int j = 0; j < U; ++j) {
                int kk = k + j;
                int s = __shfl(sv, kk < navail ? kk : navail - 1);
                float w = (kk < navail) ? 1.0f : 0.0f;
                a[j] += w * ldt(table, (size_t)s * DIM + lane);
            }
        }
    }
    float acc = 0.0f;
#pragma unroll
    for (int j = 0; j < U; ++j) acc += a[j];
    float inv = 1.0f / fmaxf((float)(end - beg), 1.0f);
    float r = acc * inv;
    if (NT) {
        __builtin_nontemporal_store(r, &out[(size_t)wid * DIM + lane]);
    } else {
        out[(size_t)wid * DIM + lane] = r;
    }
    if (out16) out16[(size_t)wid * DIM + lane] = f2bf(r);
}

// ===========================================================================
// Last-resort fallback (atomic path).
// ===========================================================================
__global__ void deg_kernel(const int* __restrict__ src,
                           const int* __restrict__ dst,
                           float* __restrict__ deg_src,
                           float* __restrict__ deg_dst) {
    int e = blockIdx.x * blockDim.x + threadIdx.x;
    if (e < N_EDGE) {
        unsafeAtomicAdd(&deg_src[src[e]], 1.0f);
        unsafeAtomicAdd(&deg_dst[dst[e]], 1.0f);
    }
}

__global__ void scatter_fwd(const int* __restrict__ src,
                            const int* __restrict__ dst,
                            const float* __restrict__ h_user,
                            float* __restrict__ rst) {
    long idx = (long)blockIdx.x * blockDim.x + threadIdx.x;
    if (idx >= (long)N_EDGE * DIM) return;
    int e = (int)(idx >> 6), d = (int)(idx & 63);
    unsafeAtomicAdd(&rst[(long)dst[e] * DIM + d], h_user[(long)src[e] * DIM + d]);
}

__global__ void norm_kernel(float* __restrict__ x,
                            const float* __restrict__ deg, long total) {
    long idx = (long)blockIdx.x * blockDim.x + threadIdx.x;
    if (idx >= total) return;
    float dg = fmaxf(deg[idx >> 6], 1.0f);
    x[idx] *= (1.0f / dg);
}

__global__ void scatter_bwd(const int* __restrict__ src,
                            const int* __restrict__ dst,
                            const float* __restrict__ rst,
                            float* __restrict__ bsrc) {
    long idx = (long)blockIdx.x * blockDim.x + threadIdx.x;
    if (idx >= (long)N_EDGE * DIM) return;
    int e = (int)(idx >> 6), d = (int)(idx & 63);
    unsafeAtomicAdd(&bsrc[(long)src[e] * DIM + d], rst[(long)dst[e] * DIM + d]);
}

extern "C" void kernel_launch(void* const* d_in, const int* in_sizes, int n_in,
                              void* d_out, int out_size, void* d_ws, size_t ws_size,
                              hipStream_t stream) {
    const float* h_user   = (const float*)d_in[0];
    const int*   edge_src = (const int*)d_in[2];
    const int*   edge_dst = (const int*)d_in[3];

    float* bsrc = (float*)d_out;                   // [N_USER, DIM]
    float* rst  = bsrc + (size_t)N_USER * DIM;     // [N_GROUP, DIM]

    const int BLK = 256;
    const int grid_e = (N_EDGE + BLK - 1) / BLK;

    // ---- scratch layout (header kept fallback-compatible) ---------------
    int* ws      = (int*)d_ws;
    int* cnt_dst = ws;                              // N_GROUP        (fallback only)
    int* off_dst = cnt_dst + N_GROUP;               // N_GROUP + 1
    int* cnt_src = off_dst + N_GROUP + 1;           // N_USER         (fallback only)
    int* off_src = cnt_src + N_USER;                // N_USER + 1
    int* cur_dst = off_src + N_USER + 1;            // N_GROUP        (fallback only)
    int* cur_src = cur_dst + N_GROUP;               // N_USER         (fallback only)
    int* partial = cur_src + N_USER;                // 256
    int* bucket_dst = partial + 256;                // N_EDGE (fallback only)
    int* bucket_src = bucket_dst + N_EDGE;          // N_EDGE (fallback only)
    unsigned short* r16 = (unsigned short*)(bucket_src + N_EDGE);  // N_GROUP*DIM
    unsigned short* h16 = r16 + (size_t)N_GROUP * DIM;             // N_USER*DIM
    // multisplit extras (8B-aligned tail)
    size_t tail = ((size_t)((char*)(h16 + (size_t)N_USER * DIM) - (char*)d_ws) + 7) & ~(size_t)7;
    int* curs_cd = (int*)((char*)d_ws + tail);      // C_DST * 16 (line-padded)
    int* curs_cs = curs_cd + C_DST * 16;            // C_SRC * 16
    int* ccnt_d  = curs_cs + C_SRC * 16;            // C_DST  coarse counts
    int* ccnt_s  = ccnt_d + C_DST;                  // C_SRC  coarse counts
    int* coff_d  = ccnt_s + C_SRC;                  // C_DST + 1
    int* coff_s  = coff_d + C_DST + 1;              // C_SRC + 1
    size_t tail2 = ((size_t)((char*)(coff_s + C_SRC + 1) - (char*)d_ws) + 7) & ~(size_t)7;
    uint32* coarse_dst = (uint32*)((char*)d_ws + tail2);  // N_EDGE u32 (packed)
    uint32* coarse_src = coarse_dst + N_EDGE;             // N_EDGE u32 (packed)

    size_t need_csr1 = (size_t)((bucket_dst + N_EDGE) - ws) * sizeof(int);
    size_t need_csr2 = (size_t)((bucket_src + N_EDGE) - ws) * sizeof(int);
    size_t need_r16  = need_csr2 + (size_t)N_GROUP * DIM * 2;
    size_t need_full = need_r16 + (size_t)N_USER * DIM * 2;
    size_t need_ms   = (size_t)((char*)(coarse_src + N_EDGE) - (char*)d_ws);

    int nb_dst = (N_GROUP + SCAN_ELEMS - 1) / SCAN_ELEMS;
    int nb_src = (N_USER + SCAN_ELEMS - 1) / SCAN_ELEMS;

    if (ws_size >= need_ms) {
        // ---- multisplit + fused sortgather path --------------------------
        bool use_h16 = (ws_size >= need_full);
        bool use_r16 = (ws_size >= need_r16);

        hipMemsetAsync(ccnt_d, 0, (size_t)(C_DST + C_SRC) * sizeof(int), stream);

        int gridA = (N_EDGE + TILE_A - 1) / TILE_A;   // 306
        int gridP = gridA + (use_h16 ? CVT_BLOCKS : 0);
        prep_kernel<<<gridP, BLK, 0, stream>>>(edge_src, edge_dst, ccnt_d, ccnt_s,
                                               h_user, use_h16 ? h16 : nullptr, gridA);

        small_scan<<<1, 256, 0, stream>>>(ccnt_d, coff_d, curs_cd, C_DST, nullptr);
        small_scan<<<1, 256, 0, stream>>>(ccnt_s, coff_s, curs_cs, C_SRC, nullptr);

        passA<<<gridA, BLK, 0, stream>>>(edge_src, edge_dst,
                                         curs_cd, curs_cs, coarse_dst, coarse_src);

        unsigned short* r16p = use_r16 ? r16 : (unsigned short*)nullptr;
        if (use_h16) {
            sortgather<KD_SHIFT, CAP_D, 8, false, unsigned short>
                <<<C_DST, 512, 0, stream>>>(coarse_dst, coff_d, h16, rst, r16p, N_GROUP);
        } else {
            sortgather<KD_SHIFT, CAP_D, 8, false, float>
                <<<C_DST, 512, 0, stream>>>(coarse_dst, coff_d, h_user, rst, r16p, N_GROUP);
        }
        if (use_r16) {
            sortgather<KS_SHIFT, CAP_S, 4, true, unsigned short>
                <<<C_SRC, 512, 0, stream>>>(coarse_src, coff_s, r16, bsrc, nullptr, N_USER);
        } else {
            sortgather<KS_SHIFT, CAP_S, 4, true, float>
                <<<C_SRC, 512, 0, stream>>>(coarse_src, coff_s, rst, bsrc, nullptr, N_USER);
        }
        return;
    }

    if (ws_size >= need_csr2) {
        // ---- fallback: hist+scan+fused fill (round-3 structure) ---------
        bool use_h16 = (ws_size >= need_full);
        bool use_r16 = (ws_size >= need_r16);

        hipMemsetAsync(d_ws, 0, (size_t)(partial - ws) * sizeof(int), stream);

        if (use_h16) {
            long n4 = (long)N_USER * DIM / 4;
            cvt_bf16<<<(int)((n4 + BLK - 1) / BLK), BLK, 0, stream>>>(h_user, h16, n4);
        }

        hist_kernel<<<grid_e, BLK, 0, stream>>>(edge_src, edge_dst, cnt_src, cnt_dst);

        scan1_kernel<<<nb_dst, SCAN_BLOCK, 0, stream>>>(cnt_dst, off_dst, partial, N_GROUP);
        scan2_kernel<<<1, SCAN_BLOCK, 0, stream>>>(partial, nb_dst, off_dst + N_GROUP);
        scan3_kernel<<<nb_dst, SCAN_BLOCK, 0, stream>>>(off_dst, partial, N_GROUP);

        scan1_kernel<<<nb_src, SCAN_BLOCK, 0, stream>>>(cnt_src, off_src, partial, N_USER);
        scan2_kernel<<<1, SCAN_BLOCK, 0, stream>>>(partial, nb_src, off_src + N_USER);
        scan3_kernel<<<nb_src, SCAN_BLOCK, 0, stream>>>(off_src, partial, N_USER);

        fill_both<<<grid_e, BLK, 0, stream>>>(
            edge_src, edge_dst, off_src, off_dst,
            cur_src, cur_dst, bucket_src, bucket_dst);

        unsigned short* r16p = use_r16 ? r16 : (unsigned short*)nullptr;
        if (use_h16) {
            gather_kernel<N_GROUP, false, 8, unsigned short>
                <<<(N_GROUP * 64 + BLK - 1) / BLK, BLK, 0, stream>>>(
                    off_dst, bucket_dst, h16, rst, r16p);
        } else {
            gather_kernel<N_GROUP, false, 8, float>
                <<<(N_GROUP * 64 + BLK - 1) / BLK, BLK, 0, stream>>>(
                    off_dst, bucket_dst, h_user, rst, r16p);
        }
        if (use_r16) {
            gather_kernel<N_USER, true, 4, unsigned short>
                <<<(int)(((size_t)N_USER * 64 + BLK - 1) / BLK), BLK, 0, stream>>>(
                    off_src, bucket_src, r16, bsrc, nullptr);
        } else {
            gather_kernel<N_USER, true, 4, float>
                <<<(int)(((size_t)N_USER * 64 + BLK - 1) / BLK), BLK, 0, stream>>>(
                    off_src, bucket_src, rst, bsrc, nullptr);
        }
        return;
    }

    if (ws_size >= need_csr1) {
        // Sequential single-bucket path (f32 gathers).
        hipMemsetAsync(d_ws, 0, (size_t)(partial - ws) * sizeof(int), stream);
        hist_kernel<<<grid_e, BLK, 0, stream>>>(edge_src, edge_dst, cnt_src, cnt_dst);

        scan1_kernel<<<nb_dst, SCAN_BLOCK, 0, stream>>>(cnt_dst, off_dst, partial, N_GROUP);
        scan2_kernel<<<1, SCAN_BLOCK, 0, stream>>>(partial, nb_dst, off_dst + N_GROUP);
        scan3_kernel<<<nb_dst, SCAN_BLOCK, 0, stream>>>(off_dst, partial, N_GROUP);

        scan1_kernel<<<nb_src, SCAN_BLOCK, 0, stream>>>(cnt_src, off_src, partial, N_USER);
        scan2_kernel<<<1, SCAN_BLOCK, 0, stream>>>(partial, nb_src, off_src + N_USER);
        scan3_kernel<<<nb_src, SCAN_BLOCK, 0, stream>>>(off_src, partial, N_USER);

        fill_one<<<grid_e, BLK, 0, stream>>>(edge_dst, edge_src, off_dst, cur_dst, bucket_dst);
        gather_kernel<N_GROUP, false, 8, float>
            <<<(N_GROUP * 64 + BLK - 1) / BLK, BLK, 0, stream>>>(
                off_dst, bucket_dst, h_user, rst, nullptr);

        fill_one<<<grid_e, BLK, 0, stream>>>(edge_src, edge_dst, off_src, cur_src, bucket_dst);
        gather_kernel<N_USER, true, 4, float>
            <<<(int)(((size_t)N_USER * 64 + BLK - 1) / BLK), BLK, 0, stream>>>(
                off_src, bucket_dst, rst, bsrc, nullptr);
        return;
    }

    // ---- Fallback: atomic path ------------------------------------------
    float* deg_dst = (float*)d_ws;
    float* deg_src = deg_dst + N_GROUP;
    hipMemsetAsync(d_out, 0, (size_t)(N_USER + N_GROUP) * DIM * sizeof(float), stream);
    hipMemsetAsync(d_ws, 0, (size_t)(N_USER + N_GROUP) * sizeof(float), stream);

    deg_kernel<<<grid_e, BLK, 0, stream>>>(edge_src, edge_dst, deg_src, deg_dst);

    long total_ed = (long)N_EDGE * DIM;
    int grid_ed = (int)((total_ed + BLK - 1) / BLK);
    scatter_fwd<<<grid_ed, BLK, 0, stream>>>(edge_src, edge_dst, h_user, rst);
    long total_g = (long)N_GROUP * DIM;
    norm_kernel<<<(int)((total_g + BLK - 1) / BLK), BLK, 0, stream>>>(rst, deg_dst, total_g);
    scatter_bwd<<<grid_ed, BLK, 0, stream>>>(edge_src, edge_dst, rst, bsrc);
    long total_u = (long)N_USER * DIM;
    norm_kernel<<<(int)((total_u + BLK - 1) / BLK), BLK, 0, stream>>>(bsrc, deg_src, total_u);
}